// Round 2
// baseline (658.110 us; speedup 1.0000x reference)
//
#include <hip/hip_runtime.h>
#include <hip/hip_bf16.h>

typedef __bf16 bf16_t;
typedef bf16_t bf16x8 __attribute__((ext_vector_type(8)));
typedef bf16_t bf16x4 __attribute__((ext_vector_type(4)));
typedef float f32x4 __attribute__((ext_vector_type(4)));

#define SCALE 0.17677669529663687f  // 32^-0.5

#define QK_S 40    // Q/K/Oh row stride (32 cols + pad) -> 2-way max
#define P_S  168   // P row stride (160 used cols + pad) -> 2-way max
#define WQ_S 200   // staged Wqkv slice row stride

// ---------------- prep: transpose + bf16-convert weights into workspace ----
__global__ void prep_weights(const float* __restrict__ w_qkv, const float* __restrict__ w_out,
                             bf16_t* __restrict__ wqkvT, bf16_t* __restrict__ woutT) {
    int i = blockIdx.x * 256 + threadIdx.x;
    if (i < 576 * 192) {
        int o = i / 192, k = i % 192;
        float v = w_qkv[k * 576 + o];
        if (o < 192) v *= SCALE;          // fold q-scale into Wq
        wqkvT[i] = (bf16_t)v;
    }
    if (i < 192 * 192) {
        int o = i / 192, k = i % 192;
        woutT[i] = (bf16_t)w_out[k * 192 + o];
    }
}

// ---------------- fused EarthAttention3D ----------------------------------
// grid: 992 blocks (one per (b,w)); block: 9 waves, wave = one 16-token tile.
// LDS = 81664 B -> 2 blocks/CU; launch_bounds(576,5) caps VGPR at 102 so the
// 5-wave SIMDs of an 18-wave residency are placeable.
__launch_bounds__(576, 5)
__global__ void earth_attn(const float* __restrict__ x, const float* __restrict__ mask,
                           const float* __restrict__ b_qkv, const float* __restrict__ bias,
                           const float* __restrict__ b_out,
                           const bf16_t* __restrict__ wqkvT, const bf16_t* __restrict__ woutT,
                           float* __restrict__ out)
{
    __shared__ bf16_t Qb[144 * QK_S];   // 11520 B (Q, then reused for Oh; wave-private rows)
    __shared__ bf16_t Kb[144 * QK_S];   // 11520 B
    __shared__ bf16_t VT0[32 * 128];    //  8192 B  V^T tokens 0..127, XOR-swizzled
    __shared__ bf16_t VT1[32 * 32];     //  2048 B  V^T tokens 128..143 (+16 zero cols)
    __shared__ bf16_t Rg[144 * P_S];    // 48384 B  WqkvS | P (time-shared)

    const int bw   = blockIdx.x;        // = b*124 + w
    const int ww   = bw % 124;
    const int tid  = threadIdx.x;
    const int lane = tid & 63;
    const int wave = tid >> 6;          // 0..8
    const int lrow = lane & 15;
    const int lgrp = lane >> 4;         // 0..3
    const int t0   = wave << 4;         // this wave's token base

    // prologue: zero VT1 cols [16,32) once (never overwritten)
    if (tid < 64) {
        uint4 z = make_uint4(0, 0, 0, 0);
        *(uint4*)&VT1[(tid >> 1) * 32 + 16 + (tid & 1) * 8] = z;
    }

    f32x4 oacc[12];
#pragma unroll
    for (int i = 0; i < 12; ++i) oacc[i] = f32x4{0.f, 0.f, 0.f, 0.f};

    const float* xp = x + (size_t)bw * (144 * 192);

    for (int h = 0; h < 6; ++h) {
        __syncthreads();   // (A) P/VT/Kb of prev head fully consumed; Rg free

        // ---- stage Wqkv head-slice into Rg (96 rows: q|k|v x 32) ----------
        {
            const int bq = h * 32, bk = 192 + h * 32, bv_ = 384 + h * 32;
            for (int u = tid; u < 96 * 24; u += 576) {
                int r = u / 24, sg = u % 24;
                int sr = (r < 32) ? (bq + r) : (r < 64) ? (bk + r - 32) : (bv_ + r - 64);
                *(bf16x8*)&Rg[r * WQ_S + sg * 8] = *(const bf16x8*)(wqkvT + sr * 192 + sg * 8);
            }
        }

        // ---- X A-fragments straight from global fp32 (L2-hot after h=0) ---
        bf16x8 xa[6];
#pragma unroll
        for (int ks = 0; ks < 6; ++ks) {
            const float* px = xp + (t0 + lrow) * 192 + ks * 32 + lgrp * 8;
            f32x4 lo = *(const f32x4*)px;
            f32x4 hi = *(const f32x4*)(px + 4);
            bf16x8 v;
            v[0] = (bf16_t)lo[0]; v[1] = (bf16_t)lo[1]; v[2] = (bf16_t)lo[2]; v[3] = (bf16_t)lo[3];
            v[4] = (bf16_t)hi[0]; v[5] = (bf16_t)hi[1]; v[6] = (bf16_t)hi[2]; v[7] = (bf16_t)hi[3];
            xa[ks] = v;
        }
        __syncthreads();   // (B) WqkvS ready

        // ---- QKV projection for this wave's 16 tokens ---------------------
#pragma unroll
        for (int wq = 0; wq < 3; ++wq) {
#pragma unroll
            for (int nt = 0; nt < 2; ++nt) {
                f32x4 acc{0.f, 0.f, 0.f, 0.f};
#pragma unroll
                for (int ks = 0; ks < 6; ++ks) {
                    bf16x8 wf = *(const bf16x8*)&Rg[(wq * 32 + nt * 16 + lrow) * WQ_S + ks * 32 + lgrp * 8];
                    acc = __builtin_amdgcn_mfma_f32_16x16x32_bf16(xa[ks], wf, acc, 0, 0, 0);
                }
                float bvx = b_qkv[wq * 192 + h * 32 + nt * 16 + lrow];
                if (wq == 0) bvx *= SCALE;
                if (wq == 2) {               // V -> transposed, swizzled LDS
                    bf16x4 pv;
#pragma unroll
                    for (int j = 0; j < 4; ++j) pv[j] = (bf16_t)(acc[j] + bvx);
                    int row = nt * 16 + lrow;
                    if (t0 < 128) {
                        int g = (t0 >> 3) + (lgrp >> 1);
                        *(bf16x4*)&VT0[row * 128 + ((g ^ (row & 7)) << 3) + (lgrp & 1) * 4] = pv;
                    } else {
                        *(bf16x4*)&VT1[row * 32 + lgrp * 4] = pv;
                    }
                } else {                     // Q / K row-major (token-major)
                    bf16_t* dst = (wq == 0) ? Qb : Kb;
#pragma unroll
                    for (int j = 0; j < 4; ++j)
                        dst[(t0 + lgrp * 4 + j) * QK_S + nt * 16 + lrow] = (bf16_t)(acc[j] + bvx);
                }
            }
        }
        __syncthreads();   // (C) Q/K/VT ready; WqkvS consumed -> Rg reusable as P

        // ---- S^T = K Q^T + (bias+mask) as C-init; in-register softmax -----
        {
            bf16x8 qb = *(const bf16x8*)&Qb[(t0 + lrow) * QK_S + lgrp * 8];
            const float* bp = bias + ((size_t)(ww * 6 + h) * 144 + (t0 + lrow)) * 144;
            const float* mp = mask + ((size_t)bw * 144 + (t0 + lrow)) * 144;
            f32x4 s[9];
#pragma unroll
            for (int nt = 0; nt < 9; ++nt) {
                f32x4 bv = *(const f32x4*)(bp + nt * 16 + lgrp * 4);
                f32x4 mv = *(const f32x4*)(mp + nt * 16 + lgrp * 4);
                s[nt] = bv + mv;
            }
#pragma unroll
            for (int nt = 0; nt < 9; ++nt) {
                bf16x8 ka = *(const bf16x8*)&Kb[(nt * 16 + lrow) * QK_S + lgrp * 8];
                s[nt] = __builtin_amdgcn_mfma_f32_16x16x32_bf16(ka, qb, s[nt], 0, 0, 0);
            }
            // each lane owns row n = t0+lrow; m spread over (nt, lgrp*4+j)
            float mx = -1e30f;
#pragma unroll
            for (int nt = 0; nt < 9; ++nt)
#pragma unroll
                for (int j = 0; j < 4; ++j) mx = fmaxf(mx, s[nt][j]);
            mx = fmaxf(mx, __shfl_xor(mx, 16, 64));
            mx = fmaxf(mx, __shfl_xor(mx, 32, 64));
            float sum = 0.f;
#pragma unroll
            for (int nt = 0; nt < 9; ++nt)
#pragma unroll
                for (int j = 0; j < 4; ++j) { float e = __expf(s[nt][j] - mx); s[nt][j] = e; sum += e; }
            sum += __shfl_xor(sum, 16, 64);
            sum += __shfl_xor(sum, 32, 64);
            float rinv = 1.0f / sum;
#pragma unroll
            for (int nt = 0; nt < 9; ++nt) {
                bf16x4 pw;
#pragma unroll
                for (int j = 0; j < 4; ++j) pw[j] = (bf16_t)(s[nt][j] * rinv);
                *(bf16x4*)&Rg[(t0 + lrow) * P_S + nt * 16 + lgrp * 4] = pw;
            }
            uint2 z2 = make_uint2(0u, 0u);   // zero P cols [144,160) of own row
            *(uint2*)&Rg[(t0 + lrow) * P_S + 144 + lgrp * 4] = z2;
        }

        // ---- O_h = P V (P own rows; VT fenced by (C)) ---------------------
        {
            f32x4 o0{0.f, 0.f, 0.f, 0.f}, o1{0.f, 0.f, 0.f, 0.f};
            const int r0 = lrow, r1 = 16 + lrow;
#pragma unroll
            for (int ks = 0; ks < 4; ++ks) {
                bf16x8 pa = *(const bf16x8*)&Rg[(t0 + lrow) * P_S + ks * 32 + lgrp * 8];
                int g = ks * 4 + lgrp;
                bf16x8 v0 = *(const bf16x8*)&VT0[r0 * 128 + ((g ^ (r0 & 7)) << 3)];
                bf16x8 v1 = *(const bf16x8*)&VT0[r1 * 128 + ((g ^ (r1 & 7)) << 3)];
                o0 = __builtin_amdgcn_mfma_f32_16x16x32_bf16(pa, v0, o0, 0, 0, 0);
                o1 = __builtin_amdgcn_mfma_f32_16x16x32_bf16(pa, v1, o1, 0, 0, 0);
            }
            {   // tail tokens 128..159 (P cols>=144 and VT1 cols>=16 are zero)
                bf16x8 pa = *(const bf16x8*)&Rg[(t0 + lrow) * P_S + 128 + lgrp * 8];
                bf16x8 v0 = *(const bf16x8*)&VT1[r0 * 32 + lgrp * 8];
                bf16x8 v1 = *(const bf16x8*)&VT1[r1 * 32 + lgrp * 8];
                o0 = __builtin_amdgcn_mfma_f32_16x16x32_bf16(pa, v0, o0, 0, 0, 0);
                o1 = __builtin_amdgcn_mfma_f32_16x16x32_bf16(pa, v1, o1, 0, 0, 0);
            }
#pragma unroll
            for (int j = 0; j < 4; ++j) {
                Qb[(t0 + lgrp * 4 + j) * QK_S + lrow]      = (bf16_t)o0[j];   // Oh over Q (own rows)
                Qb[(t0 + lgrp * 4 + j) * QK_S + 16 + lrow] = (bf16_t)o1[j];
            }
        }

        // ---- partial out-projection: oacc += O_h @ Wout[h*32:+32, :] ------
        {
            bf16x8 oa = *(const bf16x8*)&Qb[(t0 + lrow) * QK_S + lgrp * 8];
#pragma unroll
            for (int oc = 0; oc < 12; ++oc) {
                bf16x8 wf = *(const bf16x8*)(woutT + (oc * 16 + lrow) * 192 + h * 32 + lgrp * 8);
                oacc[oc] = __builtin_amdgcn_mfma_f32_16x16x32_bf16(oa, wf, oacc[oc], 0, 0, 0);
            }
        }
    }

    // ---- epilogue: + b_out, store fp32 -----------------------------------
    float* op = out + (size_t)bw * (144 * 192);
#pragma unroll
    for (int oc = 0; oc < 12; ++oc) {
        int c = oc * 16 + lrow;
        float bo = b_out[c];
#pragma unroll
        for (int j = 0; j < 4; ++j)
            op[(t0 + lgrp * 4 + j) * 192 + c] = oacc[oc][j] + bo;
    }
}

extern "C" void kernel_launch(void* const* d_in, const int* in_sizes, int n_in,
                              void* d_out, int out_size, void* d_ws, size_t ws_size,
                              hipStream_t stream) {
    const float* x     = (const float*)d_in[0];
    const float* mask  = (const float*)d_in[1];
    const float* w_qkv = (const float*)d_in[2];
    const float* b_qkv = (const float*)d_in[3];
    const float* bias  = (const float*)d_in[4];
    const float* w_out = (const float*)d_in[5];
    const float* b_out = (const float*)d_in[6];

    bf16_t* wqkvT = (bf16_t*)d_ws;                 // 576*192 bf16
    bf16_t* woutT = wqkvT + 576 * 192;             // 192*192 bf16

    prep_weights<<<dim3((576 * 192 + 255) / 256), dim3(256), 0, stream>>>(w_qkv, w_out, wqkvT, woutT);
    earth_attn<<<dim3(992), dim3(576), 0, stream>>>(x, mask, b_qkv, bias, b_out, wqkvT, woutT,
                                                    (float*)d_out);
}

// Round 3
// 544.998 us; speedup vs baseline: 1.2075x; 1.2075x over previous
//
#include <hip/hip_runtime.h>
#include <hip/hip_bf16.h>

typedef __bf16 bf16_t;
typedef bf16_t bf16x8 __attribute__((ext_vector_type(8)));
typedef bf16_t bf16x4 __attribute__((ext_vector_type(4)));
typedef float f32x4 __attribute__((ext_vector_type(4)));

#define SCALE 0.17677669529663687f  // 32^-0.5

#define QK_S 40    // Q/K/Oh row stride (32 cols + pad)
#define P_S  160   // P row stride (144 cols + 16 zero tail)

struct Shm {
    bf16_t Qb[144 * QK_S];   // 11520 B  Q then Oh (wave-private rows)
    bf16_t Kb[144 * QK_S];   // 11520 B
    bf16_t VT0[32 * 128];    //  8192 B  V^T tokens 0..127, XOR-swizzled
    bf16_t VT1[32 * 32];     //  2048 B  V^T tokens 128..143 (+16 zero cols)
    bf16_t Pb[144 * P_S];    // 46080 B
};                           // total 79360 B -> 2 blocks/CU (158720 <= 163840)

// ---------------- prep: transpose + bf16-convert weights -------------------
__global__ void prep_weights(const float* __restrict__ w_qkv, const float* __restrict__ w_out,
                             bf16_t* __restrict__ wqkvT, bf16_t* __restrict__ woutT) {
    int i = blockIdx.x * 256 + threadIdx.x;
    if (i < 576 * 192) {
        int o = i / 192, k = i % 192;
        float v = w_qkv[k * 576 + o];
        if (o < 192) v *= SCALE;          // fold q-scale into Wq
        wqkvT[i] = (bf16_t)v;
    }
    if (i < 192 * 192) {
        int o = i / 192, k = i % 192;
        woutT[i] = (bf16_t)w_out[k * 192 + o];
    }
}

// ---------------- shared attention body ------------------------------------
// FUSED=false: write per-head O (bf16) to Og, out-proj done by out_proj kernel.
// FUSED=true : accumulate out-projection in registers, write fp32 out directly.
template<bool FUSED>
__device__ __forceinline__ void attn_body(Shm& sm,
    const float* __restrict__ x, const float* __restrict__ mask,
    const float* __restrict__ b_qkv, const float* __restrict__ bias,
    const bf16_t* __restrict__ wqkvT, const bf16_t* __restrict__ woutT,
    const float* __restrict__ b_out, bf16_t* __restrict__ Og, float* __restrict__ out)
{
    const int bw   = blockIdx.x;        // = b*124 + w
    const int ww   = bw % 124;
    const int tid  = threadIdx.x;
    const int lane = tid & 63;
    const int wave = tid >> 6;          // 0..8
    const int lrow = lane & 15;
    const int lgrp = lane >> 4;         // 0..3
    const int t0   = wave << 4;

    if (tid < 64) {   // VT1 cols [16,32) stay zero
        uint4 z = make_uint4(0, 0, 0, 0);
        *(uint4*)&sm.VT1[(tid >> 1) * 32 + 16 + (tid & 1) * 8] = z;
    }

    f32x4 oacc[FUSED ? 12 : 1];
    if (FUSED) {
#pragma unroll
        for (int i = 0; i < 12; ++i) oacc[i] = f32x4{0.f, 0.f, 0.f, 0.f};
    }

    const float* xp = x + (size_t)bw * 27648;
    bf16_t* og = FUSED ? nullptr : (Og + (size_t)bw * 27648);

    for (int h = 0; h < 6; ++h) {
        __syncthreads();   // (A) prev head's Kb/VT fully consumed (and VT1 zeros at h=0)

        // ---- X fragments from global (L2-hot) -----------------------------
        bf16x8 xa[6];
#pragma unroll
        for (int ks = 0; ks < 6; ++ks) {
            const float* px = xp + (t0 + lrow) * 192 + ks * 32 + lgrp * 8;
            f32x4 lo = *(const f32x4*)px;
            f32x4 hi = *(const f32x4*)(px + 4);
            bf16x8 v;
            v[0] = (bf16_t)lo[0]; v[1] = (bf16_t)lo[1]; v[2] = (bf16_t)lo[2]; v[3] = (bf16_t)lo[3];
            v[4] = (bf16_t)hi[0]; v[5] = (bf16_t)hi[1]; v[6] = (bf16_t)hi[2]; v[7] = (bf16_t)hi[3];
            xa[ks] = v;
        }

        // ---- QKV projection (weights direct from global: L1-broadcast) ----
#pragma unroll
        for (int wq = 0; wq < 3; ++wq) {
#pragma unroll
            for (int nt = 0; nt < 2; ++nt) {
                f32x4 acc{0.f, 0.f, 0.f, 0.f};
#pragma unroll
                for (int ks = 0; ks < 6; ++ks) {
                    bf16x8 wf = *(const bf16x8*)(wqkvT +
                        (size_t)(wq * 192 + h * 32 + nt * 16 + lrow) * 192 + ks * 32 + lgrp * 8);
                    acc = __builtin_amdgcn_mfma_f32_16x16x32_bf16(xa[ks], wf, acc, 0, 0, 0);
                }
                float bvx = b_qkv[wq * 192 + h * 32 + nt * 16 + lrow];
                if (wq == 0) bvx *= SCALE;
                if (wq == 2) {               // V -> transposed, swizzled
                    bf16x4 pv;
#pragma unroll
                    for (int j = 0; j < 4; ++j) pv[j] = (bf16_t)(acc[j] + bvx);
                    int row = nt * 16 + lrow;
                    if (t0 < 128) {
                        int g = (t0 >> 3) + (lgrp >> 1);
                        *(bf16x4*)&sm.VT0[row * 128 + ((g ^ (row & 7)) << 3) + (lgrp & 1) * 4] = pv;
                    } else {
                        *(bf16x4*)&sm.VT1[row * 32 + lgrp * 4] = pv;
                    }
                } else {                     // Q / K token-major
                    bf16_t* dst = (wq == 0) ? sm.Qb : sm.Kb;
#pragma unroll
                    for (int j = 0; j < 4; ++j)
                        dst[(t0 + lgrp * 4 + j) * QK_S + nt * 16 + lrow] = (bf16_t)(acc[j] + bvx);
                }
            }
        }

        // ---- bias+mask loads issued BEFORE barrier (latency hides) --------
        f32x4 s[9];
        {
            const float* bp = bias + ((size_t)(ww * 6 + h) * 144 + (t0 + lrow)) * 144;
            const float* mp = mask + ((size_t)bw * 144 + (t0 + lrow)) * 144;
#pragma unroll
            for (int nt = 0; nt < 9; ++nt) {
                f32x4 bv = *(const f32x4*)(bp + nt * 16 + lgrp * 4);
                f32x4 mv = *(const f32x4*)(mp + nt * 16 + lgrp * 4);
                s[nt] = bv + mv;
            }
        }
        __syncthreads();   // (C) Kb/VT ready

        // ---- S^T = K Q^T + (bias+mask); in-register softmax ---------------
        {
            bf16x8 qb = *(const bf16x8*)&sm.Qb[(t0 + lrow) * QK_S + lgrp * 8];
#pragma unroll
            for (int nt = 0; nt < 9; ++nt) {
                bf16x8 ka = *(const bf16x8*)&sm.Kb[(nt * 16 + lrow) * QK_S + lgrp * 8];
                s[nt] = __builtin_amdgcn_mfma_f32_16x16x32_bf16(ka, qb, s[nt], 0, 0, 0);
            }
            float mx = -1e30f;
#pragma unroll
            for (int nt = 0; nt < 9; ++nt)
#pragma unroll
                for (int j = 0; j < 4; ++j) mx = fmaxf(mx, s[nt][j]);
            mx = fmaxf(mx, __shfl_xor(mx, 16, 64));
            mx = fmaxf(mx, __shfl_xor(mx, 32, 64));
            float sum = 0.f;
#pragma unroll
            for (int nt = 0; nt < 9; ++nt)
#pragma unroll
                for (int j = 0; j < 4; ++j) { float e = __expf(s[nt][j] - mx); s[nt][j] = e; sum += e; }
            sum += __shfl_xor(sum, 16, 64);
            sum += __shfl_xor(sum, 32, 64);
            float rinv = 1.0f / sum;
#pragma unroll
            for (int nt = 0; nt < 9; ++nt) {
                bf16x4 pw;
#pragma unroll
                for (int j = 0; j < 4; ++j) pw[j] = (bf16_t)(s[nt][j] * rinv);
                *(bf16x4*)&sm.Pb[(t0 + lrow) * P_S + nt * 16 + lgrp * 4] = pw;
            }
            uint2 z2 = make_uint2(0u, 0u);   // zero P cols [144,160)
            *(uint2*)&sm.Pb[(t0 + lrow) * P_S + 144 + lgrp * 4] = z2;
        }

        // ---- O_h = P V (own P rows; VT fenced by (C)) ----------------------
        {
            f32x4 o0{0.f, 0.f, 0.f, 0.f}, o1{0.f, 0.f, 0.f, 0.f};
            const int r0 = lrow, r1 = 16 + lrow;
#pragma unroll
            for (int ks = 0; ks < 4; ++ks) {
                bf16x8 pa = *(const bf16x8*)&sm.Pb[(t0 + lrow) * P_S + ks * 32 + lgrp * 8];
                int g = ks * 4 + lgrp;
                bf16x8 v0 = *(const bf16x8*)&sm.VT0[r0 * 128 + ((g ^ (r0 & 7)) << 3)];
                bf16x8 v1 = *(const bf16x8*)&sm.VT0[r1 * 128 + ((g ^ (r1 & 7)) << 3)];
                o0 = __builtin_amdgcn_mfma_f32_16x16x32_bf16(pa, v0, o0, 0, 0, 0);
                o1 = __builtin_amdgcn_mfma_f32_16x16x32_bf16(pa, v1, o1, 0, 0, 0);
            }
            {   // tail tokens 128..159 (zeros in P[144:) and VT1[:,16:))
                bf16x8 pa = *(const bf16x8*)&sm.Pb[(t0 + lrow) * P_S + 128 + lgrp * 8];
                bf16x8 v0 = *(const bf16x8*)&sm.VT1[r0 * 32 + lgrp * 8];
                bf16x8 v1 = *(const bf16x8*)&sm.VT1[r1 * 32 + lgrp * 8];
                o0 = __builtin_amdgcn_mfma_f32_16x16x32_bf16(pa, v0, o0, 0, 0, 0);
                o1 = __builtin_amdgcn_mfma_f32_16x16x32_bf16(pa, v1, o1, 0, 0, 0);
            }
#pragma unroll
            for (int j = 0; j < 4; ++j) {
                sm.Qb[(t0 + lgrp * 4 + j) * QK_S + lrow]      = (bf16_t)o0[j];
                sm.Qb[(t0 + lgrp * 4 + j) * QK_S + 16 + lrow] = (bf16_t)o1[j];
            }
        }

        if (FUSED) {
            bf16x8 oa = *(const bf16x8*)&sm.Qb[(t0 + lrow) * QK_S + lgrp * 8];
#pragma unroll
            for (int oc = 0; oc < 12; ++oc) {
                bf16x8 wf = *(const bf16x8*)(woutT + (oc * 16 + lrow) * 192 + h * 32 + lgrp * 8);
                oacc[oc] = __builtin_amdgcn_mfma_f32_16x16x32_bf16(oa, wf, oacc[oc], 0, 0, 0);
            }
        } else {
            // coalesced bf16 O write: own 16 rows via Qb round-trip
            *(bf16x8*)(og + (size_t)(t0 + lrow) * 192 + h * 32 + lgrp * 8) =
                *(const bf16x8*)&sm.Qb[(t0 + lrow) * QK_S + lgrp * 8];
        }
    }

    if (FUSED) {
        float* op = out + (size_t)bw * 27648;
#pragma unroll
        for (int oc = 0; oc < 12; ++oc) {
            int c = oc * 16 + lrow;
            float bo = b_out[c];
#pragma unroll
            for (int j = 0; j < 4; ++j)
                op[(t0 + lgrp * 4 + j) * 192 + c] = oacc[oc][j] + bo;
        }
    }
}

__global__ __launch_bounds__(576, 4)
void earth_attn_split(const float* __restrict__ x, const float* __restrict__ mask,
                      const float* __restrict__ b_qkv, const float* __restrict__ bias,
                      const bf16_t* __restrict__ wqkvT, bf16_t* __restrict__ Og)
{
    __shared__ Shm sm;
    attn_body<false>(sm, x, mask, b_qkv, bias, wqkvT, nullptr, nullptr, Og, nullptr);
}

__global__ __launch_bounds__(576, 2)
void earth_attn_fused(const float* __restrict__ x, const float* __restrict__ mask,
                      const float* __restrict__ b_qkv, const float* __restrict__ bias,
                      const bf16_t* __restrict__ wqkvT, const bf16_t* __restrict__ woutT,
                      const float* __restrict__ b_out, float* __restrict__ out)
{
    __shared__ Shm sm;
    attn_body<true>(sm, x, mask, b_qkv, bias, wqkvT, woutT, b_out, nullptr, out);
}

// ---------------- out-projection GEMM: out = O @ w_out + b_out -------------
__global__ __launch_bounds__(256, 4)
void out_proj(const bf16_t* __restrict__ Og, const bf16_t* __restrict__ woutT,
              const float* __restrict__ b_out, float* __restrict__ out)
{
    const int tid  = threadIdx.x;
    const int lane = tid & 63;
    const int wave = tid >> 6;          // 0..3
    const int lrow = lane & 15;
    const int lgrp = lane >> 4;
    const size_t row0 = (size_t)blockIdx.x * 64 + wave * 16;

    bf16x8 af[6];
#pragma unroll
    for (int ks = 0; ks < 6; ++ks)
        af[ks] = *(const bf16x8*)(Og + (row0 + lrow) * 192 + ks * 32 + lgrp * 8);

#pragma unroll
    for (int oc = 0; oc < 12; ++oc) {
        float b = b_out[oc * 16 + lrow];
        f32x4 acc{b, b, b, b};
#pragma unroll
        for (int ks = 0; ks < 6; ++ks) {
            bf16x8 wf = *(const bf16x8*)(woutT + (oc * 16 + lrow) * 192 + ks * 32 + lgrp * 8);
            acc = __builtin_amdgcn_mfma_f32_16x16x32_bf16(af[ks], wf, acc, 0, 0, 0);
        }
#pragma unroll
        for (int j = 0; j < 4; ++j)
            out[(row0 + lgrp * 4 + j) * 192 + oc * 16 + lrow] = acc[j];
    }
}

extern "C" void kernel_launch(void* const* d_in, const int* in_sizes, int n_in,
                              void* d_out, int out_size, void* d_ws, size_t ws_size,
                              hipStream_t stream) {
    const float* x     = (const float*)d_in[0];
    const float* mask  = (const float*)d_in[1];
    const float* w_qkv = (const float*)d_in[2];
    const float* b_qkv = (const float*)d_in[3];
    const float* bias  = (const float*)d_in[4];
    const float* w_out = (const float*)d_in[5];
    const float* b_out = (const float*)d_in[6];

    bf16_t* wqkvT = (bf16_t*)d_ws;                 // 576*192 bf16
    bf16_t* woutT = wqkvT + 576 * 192;             // 192*192 bf16
    bf16_t* Og    = woutT + 192 * 192;             // 992*144*192 bf16 (54.9 MB)

    const size_t need = (size_t)(576 * 192 + 192 * 192) * 2 + (size_t)992 * 27648 * 2;

    prep_weights<<<dim3(432), dim3(256), 0, stream>>>(w_qkv, w_out, wqkvT, woutT);

    if (ws_size >= need) {
        earth_attn_split<<<dim3(992), dim3(576), 0, stream>>>(x, mask, b_qkv, bias, wqkvT, Og);
        out_proj<<<dim3(2232), dim3(256), 0, stream>>>(Og, woutT, b_out, (float*)d_out);
    } else {
        earth_attn_fused<<<dim3(992), dim3(576), 0, stream>>>(x, mask, b_qkv, bias, wqkvT,
                                                              woutT, b_out, (float*)d_out);
    }
}

// Round 4
// 509.504 us; speedup vs baseline: 1.2917x; 1.0697x over previous
//
#include <hip/hip_runtime.h>
#include <hip/hip_bf16.h>

typedef __bf16 bf16_t;
typedef bf16_t bf16x8 __attribute__((ext_vector_type(8)));
typedef bf16_t bf16x4 __attribute__((ext_vector_type(4)));
typedef float f32x4 __attribute__((ext_vector_type(4)));

#define SCALE 0.17677669529663687f  // 32^-0.5

// ======================= prep: weights -> bf16, transposed =================
__global__ void prep_weights(const float* __restrict__ w_qkv, const float* __restrict__ w_out,
                             bf16_t* __restrict__ wqkvT, bf16_t* __restrict__ woutT) {
    int i = blockIdx.x * 256 + threadIdx.x;
    if (i < 576 * 192) {
        int o = i / 192, k = i % 192;
        float v = w_qkv[k * 576 + o];
        if (o < 192) v *= SCALE;          // fold q-scale into Wq
        wqkvT[i] = (bf16_t)v;
    }
    if (i < 192 * 192) {
        int o = i / 192, k = i % 192;
        woutT[i] = (bf16_t)w_out[k * 192 + o];
    }
}

// zero Vt cols [144,160) so padded-K PV MFMA adds exact zeros (ws is poisoned)
__global__ void zero_vt_tail(bf16_t* __restrict__ Vt) {
    int r = blockIdx.x * 256 + threadIdx.x;   // 992*6*32 = 190464 rows
    if (r < 190464) {
        uint4 z = make_uint4(0, 0, 0, 0);
        *(uint4*)&Vt[(size_t)r * 160 + 144] = z;
        *(uint4*)&Vt[(size_t)r * 160 + 152] = z;
    }
}

// ======================= kernel 1: QKV projection GEMM ======================
// grid 1116 x 256 thr (4 waves); wave handles 32 rows (2 x 16-row tiles).
// Writes Qg/Kg as [bw][h][n][32] bf16 (Q scaled+biased), V transposed into
// Vt [bw][h][32][160] (cols 144..159 pre-zeroed by zero_vt_tail).
__global__ __launch_bounds__(256, 4)
void qkv_gemm(const float* __restrict__ x, const float* __restrict__ b_qkv,
              const bf16_t* __restrict__ wqkvT,
              bf16_t* __restrict__ Qg, bf16_t* __restrict__ Kg, bf16_t* __restrict__ Vt)
{
    __shared__ bf16_t T[4][2][16 * 40];   // per-wave transpose tiles (10240 B)
    const int tid  = threadIdx.x;
    const int lane = tid & 63;
    const int wave = tid >> 6;
    const int lrow = lane & 15;
    const int lgrp = lane >> 4;
    const int r0   = blockIdx.x * 128 + wave * 32;   // wave's 32-row base

    // ---- X fragments (fp32 -> bf16), rows r0+tt*16+lrow --------------------
    bf16x8 af[2][6];
#pragma unroll
    for (int tt = 0; tt < 2; ++tt)
#pragma unroll
        for (int ks = 0; ks < 6; ++ks) {
            const float* px = x + (size_t)(r0 + tt * 16 + lrow) * 192 + ks * 32 + lgrp * 8;
            f32x4 lo = *(const f32x4*)px;
            f32x4 hi = *(const f32x4*)(px + 4);
            bf16x8 v;
            v[0] = (bf16_t)lo[0]; v[1] = (bf16_t)lo[1]; v[2] = (bf16_t)lo[2]; v[3] = (bf16_t)lo[3];
            v[4] = (bf16_t)hi[0]; v[5] = (bf16_t)hi[1]; v[6] = (bf16_t)hi[2]; v[7] = (bf16_t)hi[3];
            af[tt][ks] = v;
        }

    // ---- Q/K chunks: hc 0..5 = Q heads, 6..11 = K heads ---------------------
#pragma unroll
    for (int hc = 0; hc < 12; ++hc) {
        f32x4 a[2][2];
#pragma unroll
        for (int tt = 0; tt < 2; ++tt)
#pragma unroll
            for (int nt = 0; nt < 2; ++nt) a[tt][nt] = f32x4{0.f, 0.f, 0.f, 0.f};
#pragma unroll
        for (int ks = 0; ks < 6; ++ks) {
            bf16x8 wf0 = *(const bf16x8*)(wqkvT + (size_t)(hc * 32 + lrow) * 192 + ks * 32 + lgrp * 8);
            bf16x8 wf1 = *(const bf16x8*)(wqkvT + (size_t)(hc * 32 + 16 + lrow) * 192 + ks * 32 + lgrp * 8);
#pragma unroll
            for (int tt = 0; tt < 2; ++tt) {
                a[tt][0] = __builtin_amdgcn_mfma_f32_16x16x32_bf16(af[tt][ks], wf0, a[tt][0], 0, 0, 0);
                a[tt][1] = __builtin_amdgcn_mfma_f32_16x16x32_bf16(af[tt][ks], wf1, a[tt][1], 0, 0, 0);
            }
        }
        float b0 = b_qkv[hc * 32 + lrow], b1 = b_qkv[hc * 32 + 16 + lrow];
        if (hc < 6) { b0 *= SCALE; b1 *= SCALE; }
        const int h = (hc < 6) ? hc : hc - 6;
        bf16_t* dst = (hc < 6) ? Qg : Kg;
#pragma unroll
        for (int tt = 0; tt < 2; ++tt) {
#pragma unroll
            for (int j = 0; j < 4; ++j) {
                T[wave][tt][(lgrp * 4 + j) * 40 + lrow]      = (bf16_t)(a[tt][0][j] + b0);
                T[wave][tt][(lgrp * 4 + j) * 40 + 16 + lrow] = (bf16_t)(a[tt][1][j] + b1);
            }
            bf16x8 val = *(const bf16x8*)&T[wave][tt][lrow * 40 + lgrp * 8];
            int tk = r0 + tt * 16 + lrow, bw = tk / 144, n = tk % 144;
            *(bf16x8*)&dst[((size_t)(bw * 6 + h) * 144 + n) * 32 + lgrp * 8] = val;
        }
    }

    // ---- V chunks: direct transposed store ----------------------------------
#pragma unroll
    for (int hv = 0; hv < 6; ++hv) {
        f32x4 a[2][2];
#pragma unroll
        for (int tt = 0; tt < 2; ++tt)
#pragma unroll
            for (int nt = 0; nt < 2; ++nt) a[tt][nt] = f32x4{0.f, 0.f, 0.f, 0.f};
#pragma unroll
        for (int ks = 0; ks < 6; ++ks) {
            bf16x8 wf0 = *(const bf16x8*)(wqkvT + (size_t)(384 + hv * 32 + lrow) * 192 + ks * 32 + lgrp * 8);
            bf16x8 wf1 = *(const bf16x8*)(wqkvT + (size_t)(384 + hv * 32 + 16 + lrow) * 192 + ks * 32 + lgrp * 8);
#pragma unroll
            for (int tt = 0; tt < 2; ++tt) {
                a[tt][0] = __builtin_amdgcn_mfma_f32_16x16x32_bf16(af[tt][ks], wf0, a[tt][0], 0, 0, 0);
                a[tt][1] = __builtin_amdgcn_mfma_f32_16x16x32_bf16(af[tt][ks], wf1, a[tt][1], 0, 0, 0);
            }
        }
        float b0 = b_qkv[384 + hv * 32 + lrow], b1 = b_qkv[384 + hv * 32 + 16 + lrow];
#pragma unroll
        for (int tt = 0; tt < 2; ++tt) {
            int r  = r0 + tt * 16 + lgrp * 4;     // 4-token group never straddles bw (4|144)
            int bw = r / 144, n = r % 144;
            size_t base = ((size_t)(bw * 6 + hv) * 32) * 160;
            bf16x4 v0, v1;
#pragma unroll
            for (int j = 0; j < 4; ++j) { v0[j] = (bf16_t)(a[tt][0][j] + b0); v1[j] = (bf16_t)(a[tt][1][j] + b1); }
            *(bf16x4*)&Vt[base + (size_t)lrow * 160 + n]        = v0;   // d = lrow
            *(bf16x4*)&Vt[base + (size_t)(16 + lrow) * 160 + n] = v1;   // d = 16+lrow
        }
    }
}

// ======================= kernel 2: attention (barrier-free) =================
// grid 13392 x 256 thr (4 waves). wave-task = (bw, h, 16-q-token tile).
// LDS: wave-private P tile only (stride 168 -> conflict-free b128).
__global__ __launch_bounds__(256, 4)
void earth_attn_v2(const bf16_t* __restrict__ Qg, const bf16_t* __restrict__ Kg,
                   const bf16_t* __restrict__ Vt,
                   const float* __restrict__ mask, const float* __restrict__ bias,
                   bf16_t* __restrict__ Og)
{
    __shared__ bf16_t P[4][16 * 168];   // 21504 B -> 7 blocks/CU LDS-wise
    const int tid  = threadIdx.x;
    const int lane = tid & 63;
    const int wave = tid >> 6;
    const int lrow = lane & 15;
    const int lgrp = lane >> 4;

    const int wid = blockIdx.x * 4 + wave;   // 0..53567
    const int bw  = wid / 54;
    const int rem = wid % 54;
    const int h   = rem / 9;
    const int t0  = (rem % 9) * 16;
    const int ww  = bw % 124;

    const size_t kbase = ((size_t)(bw * 6 + h) * 144) * 32;
    const size_t vbase = ((size_t)(bw * 6 + h) * 32) * 160;

    // Q fragment (A/B layouts identical: lane -> row lane&15, k-slice lgrp*8)
    bf16x8 qa = *(const bf16x8*)&Qg[kbase + (size_t)(t0 + lrow) * 32 + lgrp * 8];

    // S^T = K Q^T with bias+mask as C-init (lane owns q-row t0+lrow)
    const float* bp = bias + ((size_t)(ww * 6 + h) * 144 + (t0 + lrow)) * 144;
    const float* mp = mask + ((size_t)bw * 144 + (t0 + lrow)) * 144;
    f32x4 s[9];
#pragma unroll
    for (int nt = 0; nt < 9; ++nt) {
        f32x4 bv = *(const f32x4*)(bp + nt * 16 + lgrp * 4);
        f32x4 mv = *(const f32x4*)(mp + nt * 16 + lgrp * 4);
        s[nt] = bv + mv;
    }
#pragma unroll
    for (int nt = 0; nt < 9; ++nt) {
        bf16x8 ka = *(const bf16x8*)&Kg[kbase + (size_t)(nt * 16 + lrow) * 32 + lgrp * 8];
        s[nt] = __builtin_amdgcn_mfma_f32_16x16x32_bf16(ka, qa, s[nt], 0, 0, 0);
    }

    // in-register softmax over m (spread across lgrp: xor 16, 32)
    float mx = -1e30f;
#pragma unroll
    for (int nt = 0; nt < 9; ++nt)
#pragma unroll
        for (int j = 0; j < 4; ++j) mx = fmaxf(mx, s[nt][j]);
    mx = fmaxf(mx, __shfl_xor(mx, 16, 64));
    mx = fmaxf(mx, __shfl_xor(mx, 32, 64));
    float sum = 0.f;
#pragma unroll
    for (int nt = 0; nt < 9; ++nt)
#pragma unroll
        for (int j = 0; j < 4; ++j) { float e = __expf(s[nt][j] - mx); s[nt][j] = e; sum += e; }
    sum += __shfl_xor(sum, 16, 64);
    sum += __shfl_xor(sum, 32, 64);
    const float rinv = 1.0f / sum;

    // P -> wave-private LDS (row = own q-row), zero tail cols [144,160)
    bf16_t* pb = &P[wave][0];
#pragma unroll
    for (int nt = 0; nt < 9; ++nt) {
        bf16x4 pw;
#pragma unroll
        for (int j = 0; j < 4; ++j) pw[j] = (bf16_t)(s[nt][j] * rinv);
        *(bf16x4*)&pb[lrow * 168 + nt * 16 + lgrp * 4] = pw;
    }
    {
        uint2 z2 = make_uint2(0u, 0u);
        *(uint2*)&pb[lrow * 168 + 144 + lgrp * 4] = z2;
    }

    // O = P V  (Vt cols 144..159 are zeroed; P tail zeroed above)
    f32x4 o0{0.f, 0.f, 0.f, 0.f}, o1{0.f, 0.f, 0.f, 0.f};
#pragma unroll
    for (int ks = 0; ks < 5; ++ks) {
        bf16x8 pa = *(const bf16x8*)&pb[lrow * 168 + ks * 32 + lgrp * 8];
        bf16x8 v0 = *(const bf16x8*)&Vt[vbase + (size_t)lrow * 160 + ks * 32 + lgrp * 8];
        bf16x8 v1 = *(const bf16x8*)&Vt[vbase + (size_t)(16 + lrow) * 160 + ks * 32 + lgrp * 8];
        o0 = __builtin_amdgcn_mfma_f32_16x16x32_bf16(pa, v0, o0, 0, 0, 0);
        o1 = __builtin_amdgcn_mfma_f32_16x16x32_bf16(pa, v1, o1, 0, 0, 0);
    }

    // O transpose via pb reuse (wave-private; LDS ops in-order per wave)
#pragma unroll
    for (int j = 0; j < 4; ++j) {
        pb[(lgrp * 4 + j) * 168 + lrow]      = (bf16_t)o0[j];
        pb[(lgrp * 4 + j) * 168 + 16 + lrow] = (bf16_t)o1[j];
    }
    bf16x8 ov = *(const bf16x8*)&pb[lrow * 168 + lgrp * 8];
    *(bf16x8*)&Og[((size_t)bw * 144 + t0 + lrow) * 192 + h * 32 + lgrp * 8] = ov;
}

// ======================= kernel 3: out-projection GEMM ======================
__global__ __launch_bounds__(256, 4)
void out_proj(const bf16_t* __restrict__ Og, const bf16_t* __restrict__ woutT,
              const float* __restrict__ b_out, float* __restrict__ out)
{
    const int tid  = threadIdx.x;
    const int lane = tid & 63;
    const int wave = tid >> 6;
    const int lrow = lane & 15;
    const int lgrp = lane >> 4;
    const size_t row0 = (size_t)blockIdx.x * 64 + wave * 16;

    bf16x8 af[6];
#pragma unroll
    for (int ks = 0; ks < 6; ++ks)
        af[ks] = *(const bf16x8*)(Og + (row0 + lrow) * 192 + ks * 32 + lgrp * 8);

#pragma unroll
    for (int oc = 0; oc < 12; ++oc) {
        float b = b_out[oc * 16 + lrow];
        f32x4 acc{b, b, b, b};
#pragma unroll
        for (int ks = 0; ks < 6; ++ks) {
            bf16x8 wf = *(const bf16x8*)(woutT + (oc * 16 + lrow) * 192 + ks * 32 + lgrp * 8);
            acc = __builtin_amdgcn_mfma_f32_16x16x32_bf16(af[ks], wf, acc, 0, 0, 0);
        }
#pragma unroll
        for (int j = 0; j < 4; ++j)
            out[(row0 + lgrp * 4 + j) * 192 + oc * 16 + lrow] = acc[j];
    }
}

// ======================= fallback (R3 split path) ===========================
#define QK_S 40
#define P_S  160
struct Shm {
    bf16_t Qb[144 * QK_S];
    bf16_t Kb[144 * QK_S];
    bf16_t VT0[32 * 128];
    bf16_t VT1[32 * 32];
    bf16_t Pb[144 * P_S];
};

__global__ __launch_bounds__(576, 4)
void earth_attn_split(const float* __restrict__ x, const float* __restrict__ mask,
                      const float* __restrict__ b_qkv, const float* __restrict__ bias,
                      const bf16_t* __restrict__ wqkvT, bf16_t* __restrict__ Og)
{
    __shared__ Shm sm;
    const int bw   = blockIdx.x;
    const int ww   = bw % 124;
    const int tid  = threadIdx.x;
    const int lane = tid & 63;
    const int wave = tid >> 6;
    const int lrow = lane & 15;
    const int lgrp = lane >> 4;
    const int t0   = wave << 4;

    if (tid < 64) {
        uint4 z = make_uint4(0, 0, 0, 0);
        *(uint4*)&sm.VT1[(tid >> 1) * 32 + 16 + (tid & 1) * 8] = z;
    }
    const float* xp = x + (size_t)bw * 27648;
    bf16_t* og = Og + (size_t)bw * 27648;

    for (int h = 0; h < 6; ++h) {
        __syncthreads();
        bf16x8 xa[6];
#pragma unroll
        for (int ks = 0; ks < 6; ++ks) {
            const float* px = xp + (t0 + lrow) * 192 + ks * 32 + lgrp * 8;
            f32x4 lo = *(const f32x4*)px;
            f32x4 hi = *(const f32x4*)(px + 4);
            bf16x8 v;
            v[0] = (bf16_t)lo[0]; v[1] = (bf16_t)lo[1]; v[2] = (bf16_t)lo[2]; v[3] = (bf16_t)lo[3];
            v[4] = (bf16_t)hi[0]; v[5] = (bf16_t)hi[1]; v[6] = (bf16_t)hi[2]; v[7] = (bf16_t)hi[3];
            xa[ks] = v;
        }
#pragma unroll
        for (int wq = 0; wq < 3; ++wq) {
#pragma unroll
            for (int nt = 0; nt < 2; ++nt) {
                f32x4 acc{0.f, 0.f, 0.f, 0.f};
#pragma unroll
                for (int ks = 0; ks < 6; ++ks) {
                    bf16x8 wf = *(const bf16x8*)(wqkvT +
                        (size_t)(wq * 192 + h * 32 + nt * 16 + lrow) * 192 + ks * 32 + lgrp * 8);
                    acc = __builtin_amdgcn_mfma_f32_16x16x32_bf16(xa[ks], wf, acc, 0, 0, 0);
                }
                float bvx = b_qkv[wq * 192 + h * 32 + nt * 16 + lrow];
                if (wq == 0) bvx *= SCALE;
                if (wq == 2) {
                    bf16x4 pv;
#pragma unroll
                    for (int j = 0; j < 4; ++j) pv[j] = (bf16_t)(acc[j] + bvx);
                    int row = nt * 16 + lrow;
                    if (t0 < 128) {
                        int g = (t0 >> 3) + (lgrp >> 1);
                        *(bf16x4*)&sm.VT0[row * 128 + ((g ^ (row & 7)) << 3) + (lgrp & 1) * 4] = pv;
                    } else {
                        *(bf16x4*)&sm.VT1[row * 32 + lgrp * 4] = pv;
                    }
                } else {
                    bf16_t* dst = (wq == 0) ? sm.Qb : sm.Kb;
#pragma unroll
                    for (int j = 0; j < 4; ++j)
                        dst[(t0 + lgrp * 4 + j) * QK_S + nt * 16 + lrow] = (bf16_t)(acc[j] + bvx);
                }
            }
        }
        f32x4 s[9];
        {
            const float* bp = bias + ((size_t)(ww * 6 + h) * 144 + (t0 + lrow)) * 144;
            const float* mp = mask + ((size_t)bw * 144 + (t0 + lrow)) * 144;
#pragma unroll
            for (int nt = 0; nt < 9; ++nt)
                s[nt] = *(const f32x4*)(bp + nt * 16 + lgrp * 4) + *(const f32x4*)(mp + nt * 16 + lgrp * 4);
        }
        __syncthreads();
        {
            bf16x8 qb = *(const bf16x8*)&sm.Qb[(t0 + lrow) * QK_S + lgrp * 8];
#pragma unroll
            for (int nt = 0; nt < 9; ++nt) {
                bf16x8 ka = *(const bf16x8*)&sm.Kb[(nt * 16 + lrow) * QK_S + lgrp * 8];
                s[nt] = __builtin_amdgcn_mfma_f32_16x16x32_bf16(ka, qb, s[nt], 0, 0, 0);
            }
            float mx = -1e30f;
#pragma unroll
            for (int nt = 0; nt < 9; ++nt)
#pragma unroll
                for (int j = 0; j < 4; ++j) mx = fmaxf(mx, s[nt][j]);
            mx = fmaxf(mx, __shfl_xor(mx, 16, 64));
            mx = fmaxf(mx, __shfl_xor(mx, 32, 64));
            float sum = 0.f;
#pragma unroll
            for (int nt = 0; nt < 9; ++nt)
#pragma unroll
                for (int j = 0; j < 4; ++j) { float e = __expf(s[nt][j] - mx); s[nt][j] = e; sum += e; }
            sum += __shfl_xor(sum, 16, 64);
            sum += __shfl_xor(sum, 32, 64);
            float rinv = 1.0f / sum;
#pragma unroll
            for (int nt = 0; nt < 9; ++nt) {
                bf16x4 pw;
#pragma unroll
                for (int j = 0; j < 4; ++j) pw[j] = (bf16_t)(s[nt][j] * rinv);
                *(bf16x4*)&sm.Pb[(t0 + lrow) * P_S + nt * 16 + lgrp * 4] = pw;
            }
            uint2 z2 = make_uint2(0u, 0u);
            *(uint2*)&sm.Pb[(t0 + lrow) * P_S + 144 + lgrp * 4] = z2;
        }
        {
            f32x4 o0{0.f, 0.f, 0.f, 0.f}, o1{0.f, 0.f, 0.f, 0.f};
            const int r0 = lrow, r1 = 16 + lrow;
#pragma unroll
            for (int ks = 0; ks < 4; ++ks) {
                bf16x8 pa = *(const bf16x8*)&sm.Pb[(t0 + lrow) * P_S + ks * 32 + lgrp * 8];
                int g = ks * 4 + lgrp;
                bf16x8 v0 = *(const bf16x8*)&sm.VT0[r0 * 128 + ((g ^ (r0 & 7)) << 3)];
                bf16x8 v1 = *(const bf16x8*)&sm.VT0[r1 * 128 + ((g ^ (r1 & 7)) << 3)];
                o0 = __builtin_amdgcn_mfma_f32_16x16x32_bf16(pa, v0, o0, 0, 0, 0);
                o1 = __builtin_amdgcn_mfma_f32_16x16x32_bf16(pa, v1, o1, 0, 0, 0);
            }
            {
                bf16x8 pa = *(const bf16x8*)&sm.Pb[(t0 + lrow) * P_S + 128 + lgrp * 8];
                bf16x8 v0 = *(const bf16x8*)&sm.VT1[r0 * 32 + lgrp * 8];
                bf16x8 v1 = *(const bf16x8*)&sm.VT1[r1 * 32 + lgrp * 8];
                o0 = __builtin_amdgcn_mfma_f32_16x16x32_bf16(pa, v0, o0, 0, 0, 0);
                o1 = __builtin_amdgcn_mfma_f32_16x16x32_bf16(pa, v1, o1, 0, 0, 0);
            }
#pragma unroll
            for (int j = 0; j < 4; ++j) {
                sm.Qb[(t0 + lgrp * 4 + j) * QK_S + lrow]      = (bf16_t)o0[j];
                sm.Qb[(t0 + lgrp * 4 + j) * QK_S + 16 + lrow] = (bf16_t)o1[j];
            }
        }
        *(bf16x8*)(og + (size_t)(t0 + lrow) * 192 + h * 32 + lgrp * 8) =
            *(const bf16x8*)&sm.Qb[(t0 + lrow) * QK_S + lgrp * 8];
    }
}

// ======================= launch =============================================
extern "C" void kernel_launch(void* const* d_in, const int* in_sizes, int n_in,
                              void* d_out, int out_size, void* d_ws, size_t ws_size,
                              hipStream_t stream) {
    const float* x     = (const float*)d_in[0];
    const float* mask  = (const float*)d_in[1];
    const float* w_qkv = (const float*)d_in[2];
    const float* b_qkv = (const float*)d_in[3];
    const float* bias  = (const float*)d_in[4];
    const float* w_out = (const float*)d_in[5];
    const float* b_out = (const float*)d_in[6];

    bf16_t* wqkvT = (bf16_t*)d_ws;                 // 110592
    bf16_t* woutT = wqkvT + 576 * 192;             // 36864
    bf16_t* Qg    = woutT + 192 * 192;             // 27,426,816
    bf16_t* Kg    = Qg + (size_t)992 * 6 * 144 * 32;
    bf16_t* Vt    = Kg + (size_t)992 * 6 * 144 * 32;   // 30,474,240
    bf16_t* Og    = Vt + (size_t)992 * 6 * 32 * 160;   // 27,426,816

    const size_t need_big =
        ((size_t)110592 + 36864 + 3 * 27426816 + 30474240) * sizeof(bf16_t);   // ~226 MB
    const size_t need_small = ((size_t)110592 + 36864 + 27426816) * sizeof(bf16_t);

    prep_weights<<<dim3(432), dim3(256), 0, stream>>>(w_qkv, w_out, wqkvT, woutT);

    if (ws_size >= need_big) {
        zero_vt_tail<<<dim3(744), dim3(256), 0, stream>>>(Vt);
        qkv_gemm<<<dim3(1116), dim3(256), 0, stream>>>(x, b_qkv, wqkvT, Qg, Kg, Vt);
        earth_attn_v2<<<dim3(13392), dim3(256), 0, stream>>>(Qg, Kg, Vt, mask, bias, Og);
        out_proj<<<dim3(2232), dim3(256), 0, stream>>>(Og, woutT, b_out, (float*)d_out);
    } else if (ws_size >= need_small) {
        bf16_t* OgS = woutT + 192 * 192;
        earth_attn_split<<<dim3(992), dim3(576), 0, stream>>>(x, mask, b_qkv, bias, wqkvT, OgS);
        out_proj<<<dim3(2232), dim3(256), 0, stream>>>(OgS, woutT, b_out, (float*)d_out);
    }
}

// Round 6
// 493.740 us; speedup vs baseline: 1.3329x; 1.0319x over previous
//
#include <hip/hip_runtime.h>
#include <hip/hip_bf16.h>

typedef __bf16 bf16_t;
typedef bf16_t bf16x8 __attribute__((ext_vector_type(8)));
typedef bf16_t bf16x4 __attribute__((ext_vector_type(4)));
typedef float f32x4 __attribute__((ext_vector_type(4)));

#define SCALE 0.17677669529663687f  // 32^-0.5

// ======================= prep: weights -> bf16, transposed =================
__global__ void prep_weights(const float* __restrict__ w_qkv, const float* __restrict__ w_out,
                             bf16_t* __restrict__ wqkvT, bf16_t* __restrict__ woutT) {
    int i = blockIdx.x * 256 + threadIdx.x;
    if (i < 576 * 192) {
        int o = i / 192, k = i % 192;
        float v = w_qkv[k * 576 + o];
        if (o < 192) v *= SCALE;          // fold q-scale into Wq
        wqkvT[i] = (bf16_t)v;
    }
    if (i < 192 * 192) {
        int o = i / 192, k = i % 192;
        woutT[i] = (bf16_t)w_out[k * 192 + o];
    }
}

// ======================= kernel 1: QKV projection GEMM ======================
// grid 1116 x 256 thr (4 waves); wave = 32 token-rows (2 x 16-row tiles).
// ALL 18 output chunks (Q,K,V x 6 heads) go through the LDS transpose tile and
// are stored as coalesced bf16x8 rows: Qg/Kg/Vg layout [bw][h][n][32].
__global__ __launch_bounds__(256, 4)
void qkv_gemm(const float* __restrict__ x, const float* __restrict__ b_qkv,
              const bf16_t* __restrict__ wqkvT,
              bf16_t* __restrict__ Qg, bf16_t* __restrict__ Kg, bf16_t* __restrict__ Vg)
{
    __shared__ bf16_t T[4][2][16 * 40];   // per-wave transpose tiles (10240 B)
    const int tid  = threadIdx.x;
    const int lane = tid & 63;
    const int wave = tid >> 6;
    const int lrow = lane & 15;
    const int lgrp = lane >> 4;
    const int r0   = blockIdx.x * 128 + wave * 32;   // wave's 32-row base

    // ---- X fragments (fp32 -> bf16), rows r0+tt*16+lrow --------------------
    bf16x8 af[2][6];
#pragma unroll
    for (int tt = 0; tt < 2; ++tt)
#pragma unroll
        for (int ks = 0; ks < 6; ++ks) {
            const float* px = x + (size_t)(r0 + tt * 16 + lrow) * 192 + ks * 32 + lgrp * 8;
            f32x4 lo = *(const f32x4*)px;
            f32x4 hi = *(const f32x4*)(px + 4);
            bf16x8 v;
            v[0] = (bf16_t)lo[0]; v[1] = (bf16_t)lo[1]; v[2] = (bf16_t)lo[2]; v[3] = (bf16_t)lo[3];
            v[4] = (bf16_t)hi[0]; v[5] = (bf16_t)hi[1]; v[6] = (bf16_t)hi[2]; v[7] = (bf16_t)hi[3];
            af[tt][ks] = v;
        }

    // ---- 18 chunks: hc 0..5 = Q, 6..11 = K, 12..17 = V ----------------------
#pragma unroll
    for (int hc = 0; hc < 18; ++hc) {
        f32x4 a[2][2];
#pragma unroll
        for (int tt = 0; tt < 2; ++tt)
#pragma unroll
            for (int nt = 0; nt < 2; ++nt) a[tt][nt] = f32x4{0.f, 0.f, 0.f, 0.f};
#pragma unroll
        for (int ks = 0; ks < 6; ++ks) {
            bf16x8 wf0 = *(const bf16x8*)(wqkvT + (size_t)(hc * 32 + lrow) * 192 + ks * 32 + lgrp * 8);
            bf16x8 wf1 = *(const bf16x8*)(wqkvT + (size_t)(hc * 32 + 16 + lrow) * 192 + ks * 32 + lgrp * 8);
#pragma unroll
            for (int tt = 0; tt < 2; ++tt) {
                a[tt][0] = __builtin_amdgcn_mfma_f32_16x16x32_bf16(af[tt][ks], wf0, a[tt][0], 0, 0, 0);
                a[tt][1] = __builtin_amdgcn_mfma_f32_16x16x32_bf16(af[tt][ks], wf1, a[tt][1], 0, 0, 0);
            }
        }
        float b0 = b_qkv[hc * 32 + lrow], b1 = b_qkv[hc * 32 + 16 + lrow];
        if (hc < 6) { b0 *= SCALE; b1 *= SCALE; }
        const int h = (hc < 6) ? hc : (hc < 12) ? hc - 6 : hc - 12;
        bf16_t* dst = (hc < 6) ? Qg : (hc < 12) ? Kg : Vg;
#pragma unroll
        for (int tt = 0; tt < 2; ++tt) {
#pragma unroll
            for (int j = 0; j < 4; ++j) {
                T[wave][tt][(lgrp * 4 + j) * 40 + lrow]      = (bf16_t)(a[tt][0][j] + b0);
                T[wave][tt][(lgrp * 4 + j) * 40 + 16 + lrow] = (bf16_t)(a[tt][1][j] + b1);
            }
            bf16x8 val = *(const bf16x8*)&T[wave][tt][lrow * 40 + lgrp * 8];
            int tk = r0 + tt * 16 + lrow, bw = tk / 144, n = tk % 144;
            *(bf16x8*)&dst[((size_t)(bw * 6 + h) * 144 + n) * 32 + lgrp * 8] = val;
        }
    }
}

// ======================= kernel 1b: Vg (row-major) -> Vt [32][160] ==========
// wave-private LDS tile; both global sides fully coalesced; writes zero tail.
__global__ __launch_bounds__(256, 4)
void vt_transpose(const bf16_t* __restrict__ Vg, bf16_t* __restrict__ Vt)
{
    __shared__ bf16_t tile[4][32 * 168];   // 43008 B
    const int lane = threadIdx.x & 63;
    const int wave = threadIdx.x >> 6;
    const int gid  = blockIdx.x * 4 + wave;          // (bw*6+h) in [0,5952)
    bf16_t* tl = &tile[wave][0];
    const bf16_t* src = Vg + (size_t)gid * 4608;     // 144*32
    bf16_t* dst = Vt + (size_t)gid * 5120;           // 32*160

    // phase A: coalesced 16B global reads, scalar transposed LDS writes
#pragma unroll
    for (int it = 0; it < 9; ++it) {
        int u = it * 64 + lane;
        int row = u >> 2, dc = u & 3;
        bf16x8 v = *(const bf16x8*)(src + row * 32 + dc * 8);
#pragma unroll
        for (int i = 0; i < 8; ++i) tl[(dc * 8 + i) * 168 + row] = v[i];
    }
    {   // zero cols [144,160) of own d-rows
        int d = lane >> 1, c = lane & 1;
        bf16x8 z = {};
        *(bf16x8*)&tl[d * 168 + 144 + c * 8] = z;
    }
    // phase B: contiguous 10 KB per wave out (fully coalesced)
#pragma unroll
    for (int it = 0; it < 10; ++it) {
        int u = it * 64 + lane;
        int d = u / 20, c = u % 20;
        *(bf16x8*)(dst + d * 160 + c * 8) = *(const bf16x8*)&tl[d * 168 + c * 8];
    }
}

// ======================= kernel 2: attention (barrier-free, XCD-swizzled) ==
// grid 13392 x 256 thr (4 waves). wave-task = (bw, h, 16-q-token tile).
__global__ __launch_bounds__(256, 4)
void earth_attn_v3(const bf16_t* __restrict__ Qg, const bf16_t* __restrict__ Kg,
                   const bf16_t* __restrict__ Vt,
                   const float* __restrict__ mask, const float* __restrict__ bias,
                   bf16_t* __restrict__ Og)
{
    __shared__ bf16_t P[4][16 * 168];   // 21504 B
    const int tid  = threadIdx.x;
    const int lane = tid & 63;
    const int wave = tid >> 6;
    const int lrow = lane & 15;
    const int lgrp = lane >> 4;

    // bijective XCD swizzle: nwg = 13392 = 8*1674 exactly -> contiguous chunk per XCD
    const int orig = blockIdx.x;
    const int blk  = (orig & 7) * 1674 + (orig >> 3);

    const int wid = blk * 4 + wave;   // 0..53567
    const int bw  = wid / 54;
    const int rem = wid % 54;
    const int h   = rem / 9;
    const int t0  = (rem % 9) * 16;
    const int ww  = bw % 124;

    const size_t kbase = ((size_t)(bw * 6 + h) * 144) * 32;
    const size_t vbase = ((size_t)(bw * 6 + h) * 32) * 160;

    // Q fragment (lane -> row lane&15, k-slice lgrp*8)
    bf16x8 qa = *(const bf16x8*)&Qg[kbase + (size_t)(t0 + lrow) * 32 + lgrp * 8];

    // S^T = K Q^T with bias+mask as C-init (lane owns q-row t0+lrow)
    const float* bp = bias + ((size_t)(ww * 6 + h) * 144 + (t0 + lrow)) * 144;
    const float* mp = mask + ((size_t)bw * 144 + (t0 + lrow)) * 144;
    f32x4 s[9];
#pragma unroll
    for (int nt = 0; nt < 9; ++nt) {
        f32x4 bv = *(const f32x4*)(bp + nt * 16 + lgrp * 4);
        f32x4 mv = *(const f32x4*)(mp + nt * 16 + lgrp * 4);
        s[nt] = bv + mv;
    }
#pragma unroll
    for (int nt = 0; nt < 9; ++nt) {
        bf16x8 ka = *(const bf16x8*)&Kg[kbase + (size_t)(nt * 16 + lrow) * 32 + lgrp * 8];
        s[nt] = __builtin_amdgcn_mfma_f32_16x16x32_bf16(ka, qa, s[nt], 0, 0, 0);
    }

    // in-register softmax over m (spread across lgrp: xor 16, 32)
    float mx = -1e30f;
#pragma unroll
    for (int nt = 0; nt < 9; ++nt)
#pragma unroll
        for (int j = 0; j < 4; ++j) mx = fmaxf(mx, s[nt][j]);
    mx = fmaxf(mx, __shfl_xor(mx, 16, 64));
    mx = fmaxf(mx, __shfl_xor(mx, 32, 64));
    float sum = 0.f;
#pragma unroll
    for (int nt = 0; nt < 9; ++nt)
#pragma unroll
        for (int j = 0; j < 4; ++j) { float e = __expf(s[nt][j] - mx); s[nt][j] = e; sum += e; }
    sum += __shfl_xor(sum, 16, 64);
    sum += __shfl_xor(sum, 32, 64);
    const float rinv = 1.0f / sum;

    // P -> wave-private LDS (row = own q-row), zero tail cols [144,160)
    bf16_t* pb = &P[wave][0];
#pragma unroll
    for (int nt = 0; nt < 9; ++nt) {
        bf16x4 pw;
#pragma unroll
        for (int j = 0; j < 4; ++j) pw[j] = (bf16_t)(s[nt][j] * rinv);
        *(bf16x4*)&pb[lrow * 168 + nt * 16 + lgrp * 4] = pw;
    }
    {
        uint2 z2 = make_uint2(0u, 0u);
        *(uint2*)&pb[lrow * 168 + 144 + lgrp * 4] = z2;
    }

    // O = P V  (Vt cols 144..159 zero; P tail zero)
    f32x4 o0{0.f, 0.f, 0.f, 0.f}, o1{0.f, 0.f, 0.f, 0.f};
#pragma unroll
    for (int ks = 0; ks < 5; ++ks) {
        bf16x8 pa = *(const bf16x8*)&pb[lrow * 168 + ks * 32 + lgrp * 8];
        bf16x8 v0 = *(const bf16x8*)&Vt[vbase + (size_t)lrow * 160 + ks * 32 + lgrp * 8];
        bf16x8 v1 = *(const bf16x8*)&Vt[vbase + (size_t)(16 + lrow) * 160 + ks * 32 + lgrp * 8];
        o0 = __builtin_amdgcn_mfma_f32_16x16x32_bf16(pa, v0, o0, 0, 0, 0);
        o1 = __builtin_amdgcn_mfma_f32_16x16x32_bf16(pa, v1, o1, 0, 0, 0);
    }

    // O transpose via pb reuse (wave-private; per-wave LDS ops in order)
#pragma unroll
    for (int j = 0; j < 4; ++j) {
        pb[(lgrp * 4 + j) * 168 + lrow]      = (bf16_t)o0[j];
        pb[(lgrp * 4 + j) * 168 + 16 + lrow] = (bf16_t)o1[j];
    }
    bf16x8 ov = *(const bf16x8*)&pb[lrow * 168 + lgrp * 8];
    *(bf16x8*)&Og[((size_t)bw * 144 + t0 + lrow) * 192 + h * 32 + lgrp * 8] = ov;
}

// ======================= kernel 3: out-projection GEMM ======================
__global__ __launch_bounds__(256, 4)
void out_proj(const bf16_t* __restrict__ Og, const bf16_t* __restrict__ woutT,
              const float* __restrict__ b_out, float* __restrict__ out)
{
    const int tid  = threadIdx.x;
    const int lane = tid & 63;
    const int wave = tid >> 6;
    const int lrow = lane & 15;
    const int lgrp = lane >> 4;
    const size_t row0 = (size_t)blockIdx.x * 64 + wave * 16;

    bf16x8 af[6];
#pragma unroll
    for (int ks = 0; ks < 6; ++ks)
        af[ks] = *(const bf16x8*)(Og + (row0 + lrow) * 192 + ks * 32 + lgrp * 8);

#pragma unroll
    for (int oc = 0; oc < 12; ++oc) {
        float b = b_out[oc * 16 + lrow];
        f32x4 acc{b, b, b, b};
#pragma unroll
        for (int ks = 0; ks < 6; ++ks) {
            bf16x8 wf = *(const bf16x8*)(woutT + (oc * 16 + lrow) * 192 + ks * 32 + lgrp * 8);
            acc = __builtin_amdgcn_mfma_f32_16x16x32_bf16(af[ks], wf, acc, 0, 0, 0);
        }
#pragma unroll
        for (int j = 0; j < 4; ++j)
            out[(row0 + lgrp * 4 + j) * 192 + oc * 16 + lrow] = acc[j];
    }
}

// ======================= launch =============================================
extern "C" void kernel_launch(void* const* d_in, const int* in_sizes, int n_in,
                              void* d_out, int out_size, void* d_ws, size_t ws_size,
                              hipStream_t stream) {
    const float* x     = (const float*)d_in[0];
    const float* mask  = (const float*)d_in[1];
    const float* w_qkv = (const float*)d_in[2];
    const float* b_qkv = (const float*)d_in[3];
    const float* bias  = (const float*)d_in[4];
    const float* w_out = (const float*)d_in[5];
    const float* b_out = (const float*)d_in[6];

    bf16_t* wqkvT = (bf16_t*)d_ws;                     // 110592
    bf16_t* woutT = wqkvT + 576 * 192;                 // 36864
    bf16_t* Qg    = woutT + 192 * 192;                 // 27,426,816
    bf16_t* Kg    = Qg + (size_t)992 * 6 * 144 * 32;   // 27,426,816
    bf16_t* Vt    = Kg + (size_t)992 * 6 * 144 * 32;   // 30,474,240
    bf16_t* Og    = Vt + (size_t)992 * 6 * 32 * 160;   // 27,426,816 (doubles as Vg)
    bf16_t* Vg    = Og;                                 // row-major V staging (dead before attn)

    prep_weights<<<dim3(432), dim3(256), 0, stream>>>(w_qkv, w_out, wqkvT, woutT);
    qkv_gemm<<<dim3(1116), dim3(256), 0, stream>>>(x, b_qkv, wqkvT, Qg, Kg, Vg);
    vt_transpose<<<dim3(1488), dim3(256), 0, stream>>>(Vg, Vt);
    earth_attn_v3<<<dim3(13392), dim3(256), 0, stream>>>(Qg, Kg, Vt, mask, bias, Og);
    out_proj<<<dim3(2232), dim3(256), 0, stream>>>(Og, woutT, b_out, (float*)d_out);
}

// Round 7
// 313.119 us; speedup vs baseline: 2.1018x; 1.5768x over previous
//
#include <hip/hip_runtime.h>
#include <hip/hip_bf16.h>

typedef __bf16 bf16_t;
typedef bf16_t bf16x8 __attribute__((ext_vector_type(8)));
typedef bf16_t bf16x4 __attribute__((ext_vector_type(4)));
typedef float f32x4 __attribute__((ext_vector_type(4)));

#define SCALE 0.17677669529663687f  // 32^-0.5

// Swizzled element offset within a 32x192 bf16 chunk image (row stride 384 B).
// 16B granule g=(c>>3): seg=g>>3 (128B segments), sub=(g&7)^(r&7).
// Uniform 8-granule spread per ds_read_b128 = LDS b128 bandwidth optimum.
__device__ __forceinline__ int swz_elem(int r, int c) {
    int g = c >> 3;
    return r * 192 + ((g >> 3) << 6) + (((g & 7) ^ (r & 7)) << 3) + (c & 7);
}

// async global->LDS: 16B per lane, linear dest (lane-order = image order)
__device__ __forceinline__ void stage_chunk(bf16_t* dst, const bf16_t* src, int tid) {
#pragma unroll
    for (int it = 0; it < 3; ++it) {
        int off = (it * 256 + tid) * 8;   // 3*256*8 = 6144 elems = 12288 B
        __builtin_amdgcn_global_load_lds(
            (const __attribute__((address_space(1))) unsigned int*)(src + off),
            (__attribute__((address_space(3))) unsigned int*)(dst + off),
            16, 0, 0);
    }
}

// ======================= prep: weights -> swizzled bf16 chunk images ========
// wqkvS: 18 chunks (Q h0..5 | K h0..5 | V h0..5), each 32 out-cols x 192 k.
// woutS: 6 chunks of w_out^T.  SCALE folded into Q chunks.
__global__ void prep_weights(const float* __restrict__ w_qkv, const float* __restrict__ w_out,
                             bf16_t* __restrict__ wqkvS, bf16_t* __restrict__ woutS) {
    int i = blockIdx.x * 256 + threadIdx.x;
    if (i < 576 * 192) {
        int o = i / 192, k = i % 192;
        float v = w_qkv[k * 576 + o];
        if (o < 192) v *= SCALE;
        wqkvS[(o >> 5) * 6144 + swz_elem(o & 31, k)] = (bf16_t)v;
    }
    if (i < 192 * 192) {
        int o = i / 192, k = i % 192;
        woutS[(o >> 5) * 6144 + swz_elem(o & 31, k)] = (bf16_t)w_out[k * 192 + o];
    }
}

// ======================= kernel 1: QKV projection GEMM ======================
// grid 1116 x 256 thr (4 waves); wave = 32 token-rows. Weight chunks double-
// buffered in LDS via global_load_lds; swizzle baked into global image.
__global__ __launch_bounds__(256, 4)
void qkv_gemm(const float* __restrict__ x, const float* __restrict__ b_qkv,
              const bf16_t* __restrict__ wqkvS,
              bf16_t* __restrict__ Qg, bf16_t* __restrict__ Kg, bf16_t* __restrict__ Vg)
{
    __shared__ __align__(16) bf16_t Wb[2][6144];     // 24576 B
    __shared__ __align__(16) bf16_t T[4][2][16 * 40]; // 10240 B (wave-private)
    const int tid  = threadIdx.x;
    const int lane = tid & 63;
    const int wave = tid >> 6;
    const int lrow = lane & 15;
    const int lgrp = lane >> 4;
    const int r0   = blockIdx.x * 128 + wave * 32;

    stage_chunk(&Wb[0][0], wqkvS, tid);   // chunk 0

    // X fragments (fp32 -> bf16), rows r0 + tt*16 + lrow — overlap stage drain
    bf16x8 af[2][6];
#pragma unroll
    for (int tt = 0; tt < 2; ++tt)
#pragma unroll
        for (int ks = 0; ks < 6; ++ks) {
            const float* px = x + (size_t)(r0 + tt * 16 + lrow) * 192 + ks * 32 + lgrp * 8;
            f32x4 lo = *(const f32x4*)px;
            f32x4 hi = *(const f32x4*)(px + 4);
            bf16x8 v;
            v[0] = (bf16_t)lo[0]; v[1] = (bf16_t)lo[1]; v[2] = (bf16_t)lo[2]; v[3] = (bf16_t)lo[3];
            v[4] = (bf16_t)hi[0]; v[5] = (bf16_t)hi[1]; v[6] = (bf16_t)hi[2]; v[7] = (bf16_t)hi[3];
            af[tt][ks] = v;
        }
    __syncthreads();   // chunk 0 resident

    for (int hc = 0; hc < 18; ++hc) {
        if (hc < 17) stage_chunk(&Wb[(hc + 1) & 1][0], wqkvS + (hc + 1) * 6144, tid);
        const bf16_t* wb = &Wb[hc & 1][0];

        f32x4 a[2][2];
        a[0][0] = f32x4{0.f,0.f,0.f,0.f}; a[0][1] = f32x4{0.f,0.f,0.f,0.f};
        a[1][0] = f32x4{0.f,0.f,0.f,0.f}; a[1][1] = f32x4{0.f,0.f,0.f,0.f};
#pragma unroll
        for (int ks = 0; ks < 6; ++ks) {
            bf16x8 wf0 = *(const bf16x8*)&wb[swz_elem(lrow,      ks * 32 + lgrp * 8)];
            bf16x8 wf1 = *(const bf16x8*)&wb[swz_elem(16 + lrow, ks * 32 + lgrp * 8)];
#pragma unroll
            for (int tt = 0; tt < 2; ++tt) {
                a[tt][0] = __builtin_amdgcn_mfma_f32_16x16x32_bf16(af[tt][ks], wf0, a[tt][0], 0, 0, 0);
                a[tt][1] = __builtin_amdgcn_mfma_f32_16x16x32_bf16(af[tt][ks], wf1, a[tt][1], 0, 0, 0);
            }
        }
        __syncthreads();   // chunk hc reads done; stage hc+1 drained

        // epilogue (wave-private T transpose + coalesced store) overlaps next iter
        float b0 = b_qkv[hc * 32 + lrow], b1 = b_qkv[hc * 32 + 16 + lrow];
        if (hc < 6) { b0 *= SCALE; b1 *= SCALE; }
        const int h = (hc < 6) ? hc : (hc < 12) ? hc - 6 : hc - 12;
        bf16_t* dst = (hc < 6) ? Qg : (hc < 12) ? Kg : Vg;
#pragma unroll
        for (int tt = 0; tt < 2; ++tt) {
#pragma unroll
            for (int j = 0; j < 4; ++j) {
                T[wave][tt][(lgrp * 4 + j) * 40 + lrow]      = (bf16_t)(a[tt][0][j] + b0);
                T[wave][tt][(lgrp * 4 + j) * 40 + 16 + lrow] = (bf16_t)(a[tt][1][j] + b1);
            }
            bf16x8 val = *(const bf16x8*)&T[wave][tt][lrow * 40 + lgrp * 8];
            int tk = r0 + tt * 16 + lrow, bw = tk / 144, n = tk % 144;
            *(bf16x8*)&dst[((size_t)(bw * 6 + h) * 144 + n) * 32 + lgrp * 8] = val;
        }
    }
}

// ======================= kernel 1b: Vg (row-major) -> Vt [32][160] ==========
__global__ __launch_bounds__(256, 4)
void vt_transpose(const bf16_t* __restrict__ Vg, bf16_t* __restrict__ Vt)
{
    __shared__ bf16_t tile[4][32 * 168];   // 43008 B
    const int lane = threadIdx.x & 63;
    const int wave = threadIdx.x >> 6;
    const int gid  = blockIdx.x * 4 + wave;          // (bw*6+h) in [0,5952)
    bf16_t* tl = &tile[wave][0];
    const bf16_t* src = Vg + (size_t)gid * 4608;
    bf16_t* dst = Vt + (size_t)gid * 5120;

#pragma unroll
    for (int it = 0; it < 9; ++it) {
        int u = it * 64 + lane;
        int row = u >> 2, dc = u & 3;
        bf16x8 v = *(const bf16x8*)(src + row * 32 + dc * 8);
#pragma unroll
        for (int i = 0; i < 8; ++i) tl[(dc * 8 + i) * 168 + row] = v[i];
    }
    {
        int d = lane >> 1, c = lane & 1;
        bf16x8 z = {};
        *(bf16x8*)&tl[d * 168 + 144 + c * 8] = z;
    }
#pragma unroll
    for (int it = 0; it < 10; ++it) {
        int u = it * 64 + lane;
        int d = u / 20, c = u % 20;
        *(bf16x8*)(dst + d * 160 + c * 8) = *(const bf16x8*)&tl[d * 168 + c * 8];
    }
}

// ======================= kernel 2: attention (barrier-free, XCD-swizzled) ==
__global__ __launch_bounds__(256, 4)
void earth_attn_v3(const bf16_t* __restrict__ Qg, const bf16_t* __restrict__ Kg,
                   const bf16_t* __restrict__ Vt,
                   const float* __restrict__ mask, const float* __restrict__ bias,
                   bf16_t* __restrict__ Og)
{
    __shared__ bf16_t P[4][16 * 168];
    const int tid  = threadIdx.x;
    const int lane = tid & 63;
    const int wave = tid >> 6;
    const int lrow = lane & 15;
    const int lgrp = lane >> 4;

    // bijective XCD swizzle: 13392 = 8 * 1674
    const int orig = blockIdx.x;
    const int blk  = (orig & 7) * 1674 + (orig >> 3);

    const int wid = blk * 4 + wave;
    const int bw  = wid / 54;
    const int rem = wid % 54;
    const int h   = rem / 9;
    const int t0  = (rem % 9) * 16;
    const int ww  = bw % 124;

    const size_t kbase = ((size_t)(bw * 6 + h) * 144) * 32;
    const size_t vbase = ((size_t)(bw * 6 + h) * 32) * 160;

    bf16x8 qa = *(const bf16x8*)&Qg[kbase + (size_t)(t0 + lrow) * 32 + lgrp * 8];

    const float* bp = bias + ((size_t)(ww * 6 + h) * 144 + (t0 + lrow)) * 144;
    const float* mp = mask + ((size_t)bw * 144 + (t0 + lrow)) * 144;
    f32x4 s[9];
#pragma unroll
    for (int nt = 0; nt < 9; ++nt) {
        f32x4 bv = *(const f32x4*)(bp + nt * 16 + lgrp * 4);
        f32x4 mv = *(const f32x4*)(mp + nt * 16 + lgrp * 4);
        s[nt] = bv + mv;
    }
#pragma unroll
    for (int nt = 0; nt < 9; ++nt) {
        bf16x8 ka = *(const bf16x8*)&Kg[kbase + (size_t)(nt * 16 + lrow) * 32 + lgrp * 8];
        s[nt] = __builtin_amdgcn_mfma_f32_16x16x32_bf16(ka, qa, s[nt], 0, 0, 0);
    }

    float mx = -1e30f;
#pragma unroll
    for (int nt = 0; nt < 9; ++nt)
#pragma unroll
        for (int j = 0; j < 4; ++j) mx = fmaxf(mx, s[nt][j]);
    mx = fmaxf(mx, __shfl_xor(mx, 16, 64));
    mx = fmaxf(mx, __shfl_xor(mx, 32, 64));
    float sum = 0.f;
#pragma unroll
    for (int nt = 0; nt < 9; ++nt)
#pragma unroll
        for (int j = 0; j < 4; ++j) { float e = __expf(s[nt][j] - mx); s[nt][j] = e; sum += e; }
    sum += __shfl_xor(sum, 16, 64);
    sum += __shfl_xor(sum, 32, 64);
    const float rinv = 1.0f / sum;

    bf16_t* pb = &P[wave][0];
#pragma unroll
    for (int nt = 0; nt < 9; ++nt) {
        bf16x4 pw;
#pragma unroll
        for (int j = 0; j < 4; ++j) pw[j] = (bf16_t)(s[nt][j] * rinv);
        *(bf16x4*)&pb[lrow * 168 + nt * 16 + lgrp * 4] = pw;
    }
    {
        uint2 z2 = make_uint2(0u, 0u);
        *(uint2*)&pb[lrow * 168 + 144 + lgrp * 4] = z2;
    }

    f32x4 o0{0.f, 0.f, 0.f, 0.f}, o1{0.f, 0.f, 0.f, 0.f};
#pragma unroll
    for (int ks = 0; ks < 5; ++ks) {
        bf16x8 pa = *(const bf16x8*)&pb[lrow * 168 + ks * 32 + lgrp * 8];
        bf16x8 v0 = *(const bf16x8*)&Vt[vbase + (size_t)lrow * 160 + ks * 32 + lgrp * 8];
        bf16x8 v1 = *(const bf16x8*)&Vt[vbase + (size_t)(16 + lrow) * 160 + ks * 32 + lgrp * 8];
        o0 = __builtin_amdgcn_mfma_f32_16x16x32_bf16(pa, v0, o0, 0, 0, 0);
        o1 = __builtin_amdgcn_mfma_f32_16x16x32_bf16(pa, v1, o1, 0, 0, 0);
    }

#pragma unroll
    for (int j = 0; j < 4; ++j) {
        pb[(lgrp * 4 + j) * 168 + lrow]      = (bf16_t)o0[j];
        pb[(lgrp * 4 + j) * 168 + 16 + lrow] = (bf16_t)o1[j];
    }
    bf16x8 ov = *(const bf16x8*)&pb[lrow * 168 + lgrp * 8];
    *(bf16x8*)&Og[((size_t)bw * 144 + t0 + lrow) * 192 + h * 32 + lgrp * 8] = ov;
}

// ======================= kernel 3: out-projection GEMM ======================
// grid 2232 x 256 thr (4 waves); wave = 16 rows; LDS-dbuf weight chunks.
__global__ __launch_bounds__(256, 4)
void out_proj(const bf16_t* __restrict__ Og, const bf16_t* __restrict__ woutS,
              const float* __restrict__ b_out, float* __restrict__ out)
{
    __shared__ __align__(16) bf16_t Wb[2][6144];
    const int tid  = threadIdx.x;
    const int lane = tid & 63;
    const int wave = tid >> 6;
    const int lrow = lane & 15;
    const int lgrp = lane >> 4;
    const size_t row0 = (size_t)blockIdx.x * 64 + wave * 16;

    stage_chunk(&Wb[0][0], woutS, tid);

    bf16x8 af[6];
#pragma unroll
    for (int ks = 0; ks < 6; ++ks)
        af[ks] = *(const bf16x8*)(Og + (row0 + lrow) * 192 + ks * 32 + lgrp * 8);
    __syncthreads();

#pragma unroll
    for (int c = 0; c < 6; ++c) {
        if (c < 5) stage_chunk(&Wb[(c + 1) & 1][0], woutS + (c + 1) * 6144, tid);
        const bf16_t* wb = &Wb[c & 1][0];
        float b0 = b_out[c * 32 + lrow], b1 = b_out[c * 32 + 16 + lrow];
        f32x4 a0{b0, b0, b0, b0}, a1{b1, b1, b1, b1};
#pragma unroll
        for (int ks = 0; ks < 6; ++ks) {
            bf16x8 wf0 = *(const bf16x8*)&wb[swz_elem(lrow,      ks * 32 + lgrp * 8)];
            bf16x8 wf1 = *(const bf16x8*)&wb[swz_elem(16 + lrow, ks * 32 + lgrp * 8)];
            a0 = __builtin_amdgcn_mfma_f32_16x16x32_bf16(af[ks], wf0, a0, 0, 0, 0);
            a1 = __builtin_amdgcn_mfma_f32_16x16x32_bf16(af[ks], wf1, a1, 0, 0, 0);
        }
        __syncthreads();
#pragma unroll
        for (int j = 0; j < 4; ++j) {
            out[(row0 + lgrp * 4 + j) * 192 + c * 32 + lrow]      = a0[j];
            out[(row0 + lgrp * 4 + j) * 192 + c * 32 + 16 + lrow] = a1[j];
        }
    }
}

// ======================= launch =============================================
extern "C" void kernel_launch(void* const* d_in, const int* in_sizes, int n_in,
                              void* d_out, int out_size, void* d_ws, size_t ws_size,
                              hipStream_t stream) {
    const float* x     = (const float*)d_in[0];
    const float* mask  = (const float*)d_in[1];
    const float* w_qkv = (const float*)d_in[2];
    const float* b_qkv = (const float*)d_in[3];
    const float* bias  = (const float*)d_in[4];
    const float* w_out = (const float*)d_in[5];
    const float* b_out = (const float*)d_in[6];

    bf16_t* wqkvS = (bf16_t*)d_ws;                     // 110592 (swizzled chunks)
    bf16_t* woutS = wqkvS + 576 * 192;                 // 36864  (swizzled chunks)
    bf16_t* Qg    = woutS + 192 * 192;                 // 27,426,816
    bf16_t* Kg    = Qg + (size_t)992 * 6 * 144 * 32;   // 27,426,816
    bf16_t* Vt    = Kg + (size_t)992 * 6 * 144 * 32;   // 30,474,240
    bf16_t* Og    = Vt + (size_t)992 * 6 * 32 * 160;   // 27,426,816 (doubles as Vg)
    bf16_t* Vg    = Og;

    prep_weights<<<dim3(432), dim3(256), 0, stream>>>(w_qkv, w_out, wqkvS, woutS);
    qkv_gemm<<<dim3(1116), dim3(256), 0, stream>>>(x, b_qkv, wqkvS, Qg, Kg, Vg);
    vt_transpose<<<dim3(1488), dim3(256), 0, stream>>>(Vg, Vt);
    earth_attn_v3<<<dim3(13392), dim3(256), 0, stream>>>(Qg, Kg, Vt, mask, bias, Og);
    out_proj<<<dim3(2232), dim3(256), 0, stream>>>(Og, woutS, b_out, (float*)d_out);
}

// Round 8
// 312.995 us; speedup vs baseline: 2.1026x; 1.0004x over previous
//
#include <hip/hip_runtime.h>
#include <hip/hip_bf16.h>

typedef __bf16 bf16_t;
typedef bf16_t bf16x8 __attribute__((ext_vector_type(8)));
typedef bf16_t bf16x4 __attribute__((ext_vector_type(4)));
typedef float f32x4 __attribute__((ext_vector_type(4)));

#define SCALE 0.17677669529663687f  // 32^-0.5

// Swizzled element offset within a 32x192 bf16 chunk image (row stride 384 B).
__device__ __forceinline__ int swz_elem(int r, int c) {
    int g = c >> 3;
    return r * 192 + ((g >> 3) << 6) + (((g & 7) ^ (r & 7)) << 3) + (c & 7);
}

// async global->LDS: 16B per lane, linear dest (lane-order = image order)
__device__ __forceinline__ void stage_chunk(bf16_t* dst, const bf16_t* src, int tid) {
#pragma unroll
    for (int it = 0; it < 3; ++it) {
        int off = (it * 256 + tid) * 8;   // 3*256*8 = 6144 elems = 12288 B
        __builtin_amdgcn_global_load_lds(
            (const __attribute__((address_space(1))) unsigned int*)(src + off),
            (__attribute__((address_space(3))) unsigned int*)(dst + off),
            16, 0, 0);
    }
}

// ======================= prep: weights -> swizzled bf16 chunk images ========
__global__ void prep_weights(const float* __restrict__ w_qkv, const float* __restrict__ w_out,
                             bf16_t* __restrict__ wqkvS, bf16_t* __restrict__ woutS) {
    int i = blockIdx.x * 256 + threadIdx.x;
    if (i < 576 * 192) {
        int o = i / 192, k = i % 192;
        float v = w_qkv[k * 576 + o];
        if (o < 192) v *= SCALE;
        wqkvS[(o >> 5) * 6144 + swz_elem(o & 31, k)] = (bf16_t)v;
    }
    if (i < 192 * 192) {
        int o = i / 192, k = i % 192;
        woutS[(o >> 5) * 6144 + swz_elem(o & 31, k)] = (bf16_t)w_out[k * 192 + o];
    }
}

// ======================= kernel 1: QKV projection GEMM ======================
__global__ __launch_bounds__(256, 4)
void qkv_gemm(const float* __restrict__ x, const float* __restrict__ b_qkv,
              const bf16_t* __restrict__ wqkvS,
              bf16_t* __restrict__ Qg, bf16_t* __restrict__ Kg, bf16_t* __restrict__ Vg)
{
    __shared__ __align__(16) bf16_t Wb[2][6144];     // 24576 B
    __shared__ __align__(16) bf16_t T[4][2][16 * 40]; // 10240 B (wave-private)
    const int tid  = threadIdx.x;
    const int lane = tid & 63;
    const int wave = tid >> 6;
    const int lrow = lane & 15;
    const int lgrp = lane >> 4;
    const int r0   = blockIdx.x * 128 + wave * 32;

    stage_chunk(&Wb[0][0], wqkvS, tid);   // chunk 0

    bf16x8 af[2][6];
#pragma unroll
    for (int tt = 0; tt < 2; ++tt)
#pragma unroll
        for (int ks = 0; ks < 6; ++ks) {
            const float* px = x + (size_t)(r0 + tt * 16 + lrow) * 192 + ks * 32 + lgrp * 8;
            f32x4 lo = *(const f32x4*)px;
            f32x4 hi = *(const f32x4*)(px + 4);
            bf16x8 v;
            v[0] = (bf16_t)lo[0]; v[1] = (bf16_t)lo[1]; v[2] = (bf16_t)lo[2]; v[3] = (bf16_t)lo[3];
            v[4] = (bf16_t)hi[0]; v[5] = (bf16_t)hi[1]; v[6] = (bf16_t)hi[2]; v[7] = (bf16_t)hi[3];
            af[tt][ks] = v;
        }
    __syncthreads();   // chunk 0 resident

    for (int hc = 0; hc < 18; ++hc) {
        if (hc < 17) stage_chunk(&Wb[(hc + 1) & 1][0], wqkvS + (hc + 1) * 6144, tid);
        const bf16_t* wb = &Wb[hc & 1][0];

        f32x4 a[2][2];
        a[0][0] = f32x4{0.f,0.f,0.f,0.f}; a[0][1] = f32x4{0.f,0.f,0.f,0.f};
        a[1][0] = f32x4{0.f,0.f,0.f,0.f}; a[1][1] = f32x4{0.f,0.f,0.f,0.f};
#pragma unroll
        for (int ks = 0; ks < 6; ++ks) {
            bf16x8 wf0 = *(const bf16x8*)&wb[swz_elem(lrow,      ks * 32 + lgrp * 8)];
            bf16x8 wf1 = *(const bf16x8*)&wb[swz_elem(16 + lrow, ks * 32 + lgrp * 8)];
#pragma unroll
            for (int tt = 0; tt < 2; ++tt) {
                a[tt][0] = __builtin_amdgcn_mfma_f32_16x16x32_bf16(af[tt][ks], wf0, a[tt][0], 0, 0, 0);
                a[tt][1] = __builtin_amdgcn_mfma_f32_16x16x32_bf16(af[tt][ks], wf1, a[tt][1], 0, 0, 0);
            }
        }
        __syncthreads();   // chunk hc reads done; stage hc+1 drained

        float b0 = b_qkv[hc * 32 + lrow], b1 = b_qkv[hc * 32 + 16 + lrow];
        if (hc < 6) { b0 *= SCALE; b1 *= SCALE; }
        const int h = (hc < 6) ? hc : (hc < 12) ? hc - 6 : hc - 12;
        bf16_t* dst = (hc < 6) ? Qg : (hc < 12) ? Kg : Vg;
#pragma unroll
        for (int tt = 0; tt < 2; ++tt) {
#pragma unroll
            for (int j = 0; j < 4; ++j) {
                T[wave][tt][(lgrp * 4 + j) * 40 + lrow]      = (bf16_t)(a[tt][0][j] + b0);
                T[wave][tt][(lgrp * 4 + j) * 40 + 16 + lrow] = (bf16_t)(a[tt][1][j] + b1);
            }
            bf16x8 val = *(const bf16x8*)&T[wave][tt][lrow * 40 + lgrp * 8];
            int tk = r0 + tt * 16 + lrow, bw = tk / 144, n = tk % 144;
            *(bf16x8*)&dst[((size_t)(bw * 6 + h) * 144 + n) * 32 + lgrp * 8] = val;
        }
    }
}

// ======================= kernel 1b: Vg (row-major) -> Vt [32][160] ==========
__global__ __launch_bounds__(256, 4)
void vt_transpose(const bf16_t* __restrict__ Vg, bf16_t* __restrict__ Vt)
{
    __shared__ bf16_t tile[4][32 * 168];   // 43008 B
    const int lane = threadIdx.x & 63;
    const int wave = threadIdx.x >> 6;
    const int gid  = blockIdx.x * 4 + wave;          // (bw*6+h) in [0,5952)
    bf16_t* tl = &tile[wave][0];
    const bf16_t* src = Vg + (size_t)gid * 4608;
    bf16_t* dst = Vt + (size_t)gid * 5120;

#pragma unroll
    for (int it = 0; it < 9; ++it) {
        int u = it * 64 + lane;
        int row = u >> 2, dc = u & 3;
        bf16x8 v = *(const bf16x8*)(src + row * 32 + dc * 8);
#pragma unroll
        for (int i = 0; i < 8; ++i) tl[(dc * 8 + i) * 168 + row] = v[i];
    }
    {
        int d = lane >> 1, c = lane & 1;
        bf16x8 z = {};
        *(bf16x8*)&tl[d * 168 + 144 + c * 8] = z;
    }
#pragma unroll
    for (int it = 0; it < 10; ++it) {
        int u = it * 64 + lane;
        int d = u / 20, c = u % 20;
        *(bf16x8*)(dst + d * 160 + c * 8) = *(const bf16x8*)&tl[d * 168 + c * 8];
    }
}

// ======================= kernel 2: attention v4 =============================
// grid 13392 x 256 thr (4 waves). wave-task = (ww, b, h, 16-q-tile), ww-major
// so each XCD chunk keeps one ww's bias slice L2-hot. All global fragment
// loads hoisted into register arrays (9-deep K MLP, 10-deep V MLP).
__global__ __launch_bounds__(256, 4)
void earth_attn_v4(const bf16_t* __restrict__ Qg, const bf16_t* __restrict__ Kg,
                   const bf16_t* __restrict__ Vt,
                   const float* __restrict__ mask, const float* __restrict__ bias,
                   bf16_t* __restrict__ Og)
{
    __shared__ bf16_t P[4][16 * 168];
    const int tid  = threadIdx.x;
    const int lane = tid & 63;
    const int wave = tid >> 6;
    const int lrow = lane & 15;
    const int lgrp = lane >> 4;

    // bijective XCD swizzle: 13392 = 8 * 1674 (contiguous chunk per XCD)
    const int orig = blockIdx.x;
    const int blk  = (orig & 7) * 1674 + (orig >> 3);

    // ww-major task order: bias slice for one ww stays hot within an XCD chunk
    const int wid = blk * 4 + wave;          // 0..53567
    const int ww  = wid / 432;               // 0..123
    const int r1  = wid - ww * 432;
    const int b   = r1 / 54;                 // 0..7
    const int rem = r1 - b * 54;
    const int h   = rem / 9;
    const int t0  = (rem % 9) * 16;
    const int bw  = b * 124 + ww;

    const size_t kbase = ((size_t)(bw * 6 + h) * 144) * 32;
    const size_t vbase = ((size_t)(bw * 6 + h) * 32) * 160;

    // ---- hoisted Q + K fragment loads (10 outstanding) ---------------------
    bf16x8 qa = *(const bf16x8*)&Qg[kbase + (size_t)(t0 + lrow) * 32 + lgrp * 8];
    bf16x8 ka[9];
#pragma unroll
    for (int nt = 0; nt < 9; ++nt)
        ka[nt] = *(const bf16x8*)&Kg[kbase + (size_t)(nt * 16 + lrow) * 32 + lgrp * 8];

    // ---- bias+mask as C-init (18 more outstanding loads) -------------------
    const float* bp = bias + ((size_t)(ww * 6 + h) * 144 + (t0 + lrow)) * 144;
    const float* mp = mask + ((size_t)bw * 144 + (t0 + lrow)) * 144;
    f32x4 s[9];
#pragma unroll
    for (int nt = 0; nt < 9; ++nt) {
        f32x4 bv = *(const f32x4*)(bp + nt * 16 + lgrp * 4);
        f32x4 mv = *(const f32x4*)(mp + nt * 16 + lgrp * 4);
        s[nt] = bv + mv;
    }
#pragma unroll
    for (int nt = 0; nt < 9; ++nt)
        s[nt] = __builtin_amdgcn_mfma_f32_16x16x32_bf16(ka[nt], qa, s[nt], 0, 0, 0);

    // ---- issue V loads now; latency hides under softmax --------------------
    bf16x8 va0[5], va1[5];
#pragma unroll
    for (int ks = 0; ks < 5; ++ks) {
        va0[ks] = *(const bf16x8*)&Vt[vbase + (size_t)lrow * 160 + ks * 32 + lgrp * 8];
        va1[ks] = *(const bf16x8*)&Vt[vbase + (size_t)(16 + lrow) * 160 + ks * 32 + lgrp * 8];
    }

    // ---- softmax (lane owns q-row t0+lrow; m spread over lgrp) --------------
    float mx = -1e30f;
#pragma unroll
    for (int nt = 0; nt < 9; ++nt)
#pragma unroll
        for (int j = 0; j < 4; ++j) mx = fmaxf(mx, s[nt][j]);
    mx = fmaxf(mx, __shfl_xor(mx, 16, 64));
    mx = fmaxf(mx, __shfl_xor(mx, 32, 64));
    float sum = 0.f;
#pragma unroll
    for (int nt = 0; nt < 9; ++nt)
#pragma unroll
        for (int j = 0; j < 4; ++j) { float e = __expf(s[nt][j] - mx); s[nt][j] = e; sum += e; }
    sum += __shfl_xor(sum, 16, 64);
    sum += __shfl_xor(sum, 32, 64);
    const float rinv = 1.0f / sum;

    // ---- P -> wave-private LDS, zero tail cols [144,160) --------------------
    bf16_t* pb = &P[wave][0];
#pragma unroll
    for (int nt = 0; nt < 9; ++nt) {
        bf16x4 pw;
#pragma unroll
        for (int j = 0; j < 4; ++j) pw[j] = (bf16_t)(s[nt][j] * rinv);
        *(bf16x4*)&pb[lrow * 168 + nt * 16 + lgrp * 4] = pw;
    }
    {
        uint2 z2 = make_uint2(0u, 0u);
        *(uint2*)&pb[lrow * 168 + 144 + lgrp * 4] = z2;
    }

    // ---- hoisted P fragment reads, then PV ----------------------------------
    bf16x8 pa[5];
#pragma unroll
    for (int ks = 0; ks < 5; ++ks)
        pa[ks] = *(const bf16x8*)&pb[lrow * 168 + ks * 32 + lgrp * 8];

    f32x4 o0{0.f, 0.f, 0.f, 0.f}, o1{0.f, 0.f, 0.f, 0.f};
#pragma unroll
    for (int ks = 0; ks < 5; ++ks) {
        o0 = __builtin_amdgcn_mfma_f32_16x16x32_bf16(pa[ks], va0[ks], o0, 0, 0, 0);
        o1 = __builtin_amdgcn_mfma_f32_16x16x32_bf16(pa[ks], va1[ks], o1, 0, 0, 0);
    }

    // ---- O transpose via pb reuse, coalesced store ---------------------------
#pragma unroll
    for (int j = 0; j < 4; ++j) {
        pb[(lgrp * 4 + j) * 168 + lrow]      = (bf16_t)o0[j];
        pb[(lgrp * 4 + j) * 168 + 16 + lrow] = (bf16_t)o1[j];
    }
    bf16x8 ov = *(const bf16x8*)&pb[lrow * 168 + lgrp * 8];
    *(bf16x8*)&Og[((size_t)bw * 144 + t0 + lrow) * 192 + h * 32 + lgrp * 8] = ov;
}

// ======================= kernel 3: out-projection GEMM ======================
__global__ __launch_bounds__(256, 4)
void out_proj(const bf16_t* __restrict__ Og, const bf16_t* __restrict__ woutS,
              const float* __restrict__ b_out, float* __restrict__ out)
{
    __shared__ __align__(16) bf16_t Wb[2][6144];
    const int tid  = threadIdx.x;
    const int lane = tid & 63;
    const int wave = tid >> 6;
    const int lrow = lane & 15;
    const int lgrp = lane >> 4;
    const size_t row0 = (size_t)blockIdx.x * 64 + wave * 16;

    stage_chunk(&Wb[0][0], woutS, tid);

    bf16x8 af[6];
#pragma unroll
    for (int ks = 0; ks < 6; ++ks)
        af[ks] = *(const bf16x8*)(Og + (row0 + lrow) * 192 + ks * 32 + lgrp * 8);
    __syncthreads();

#pragma unroll
    for (int c = 0; c < 6; ++c) {
        if (c < 5) stage_chunk(&Wb[(c + 1) & 1][0], woutS + (c + 1) * 6144, tid);
        const bf16_t* wb = &Wb[c & 1][0];
        float b0 = b_out[c * 32 + lrow], b1 = b_out[c * 32 + 16 + lrow];
        f32x4 a0{b0, b0, b0, b0}, a1{b1, b1, b1, b1};
#pragma unroll
        for (int ks = 0; ks < 6; ++ks) {
            bf16x8 wf0 = *(const bf16x8*)&wb[swz_elem(lrow,      ks * 32 + lgrp * 8)];
            bf16x8 wf1 = *(const bf16x8*)&wb[swz_elem(16 + lrow, ks * 32 + lgrp * 8)];
            a0 = __builtin_amdgcn_mfma_f32_16x16x32_bf16(af[ks], wf0, a0, 0, 0, 0);
            a1 = __builtin_amdgcn_mfma_f32_16x16x32_bf16(af[ks], wf1, a1, 0, 0, 0);
        }
        __syncthreads();
#pragma unroll
        for (int j = 0; j < 4; ++j) {
            out[(row0 + lgrp * 4 + j) * 192 + c * 32 + lrow]      = a0[j];
            out[(row0 + lgrp * 4 + j) * 192 + c * 32 + 16 + lrow] = a1[j];
        }
    }
}

// ======================= launch =============================================
extern "C" void kernel_launch(void* const* d_in, const int* in_sizes, int n_in,
                              void* d_out, int out_size, void* d_ws, size_t ws_size,
                              hipStream_t stream) {
    const float* x     = (const float*)d_in[0];
    const float* mask  = (const float*)d_in[1];
    const float* w_qkv = (const float*)d_in[2];
    const float* b_qkv = (const float*)d_in[3];
    const float* bias  = (const float*)d_in[4];
    const float* w_out = (const float*)d_in[5];
    const float* b_out = (const float*)d_in[6];

    bf16_t* wqkvS = (bf16_t*)d_ws;                     // 110592 (swizzled chunks)
    bf16_t* woutS = wqkvS + 576 * 192;                 // 36864  (swizzled chunks)
    bf16_t* Qg    = woutS + 192 * 192;                 // 27,426,816
    bf16_t* Kg    = Qg + (size_t)992 * 6 * 144 * 32;   // 27,426,816
    bf16_t* Vt    = Kg + (size_t)992 * 6 * 144 * 32;   // 30,474,240
    bf16_t* Og    = Vt + (size_t)992 * 6 * 32 * 160;   // 27,426,816 (doubles as Vg)
    bf16_t* Vg    = Og;

    prep_weights<<<dim3(432), dim3(256), 0, stream>>>(w_qkv, w_out, wqkvS, woutS);
    qkv_gemm<<<dim3(1116), dim3(256), 0, stream>>>(x, b_qkv, wqkvS, Qg, Kg, Vg);
    vt_transpose<<<dim3(1488), dim3(256), 0, stream>>>(Vg, Vt);
    earth_attn_v4<<<dim3(13392), dim3(256), 0, stream>>>(Qg, Kg, Vt, mask, bias, Og);
    out_proj<<<dim3(2232), dim3(256), 0, stream>>>(Og, woutS, b_out, (float*)d_out);
}

// Round 9
// 310.991 us; speedup vs baseline: 2.1162x; 1.0064x over previous
//
#include <hip/hip_runtime.h>
#include <hip/hip_bf16.h>

typedef __bf16 bf16_t;
typedef bf16_t bf16x8 __attribute__((ext_vector_type(8)));
typedef bf16_t bf16x4 __attribute__((ext_vector_type(4)));
typedef float f32x4 __attribute__((ext_vector_type(4)));

#define SCALE 0.17677669529663687f  // 32^-0.5

// keep a loaded value live / pinned at this program point (defeats load sinking)
#define PIN(x) asm volatile("" : "+v"(x))

// Swizzled element offset within a 32x192 bf16 chunk image (row stride 384 B).
__device__ __forceinline__ int swz_elem(int r, int c) {
    int g = c >> 3;
    return r * 192 + ((g >> 3) << 6) + (((g & 7) ^ (r & 7)) << 3) + (c & 7);
}

// async global->LDS: 16B per lane, linear dest (lane-order = image order)
__device__ __forceinline__ void stage_chunk(bf16_t* dst, const bf16_t* src, int tid) {
#pragma unroll
    for (int it = 0; it < 3; ++it) {
        int off = (it * 256 + tid) * 8;   // 3*256*8 = 6144 elems = 12288 B
        __builtin_amdgcn_global_load_lds(
            (const __attribute__((address_space(1))) unsigned int*)(src + off),
            (__attribute__((address_space(3))) unsigned int*)(dst + off),
            16, 0, 0);
    }
}

// ======================= prep: weights -> swizzled bf16 chunk images ========
__global__ void prep_weights(const float* __restrict__ w_qkv, const float* __restrict__ w_out,
                             bf16_t* __restrict__ wqkvS, bf16_t* __restrict__ woutS) {
    int i = blockIdx.x * 256 + threadIdx.x;
    if (i < 576 * 192) {
        int o = i / 192, k = i % 192;
        float v = w_qkv[k * 576 + o];
        if (o < 192) v *= SCALE;
        wqkvS[(o >> 5) * 6144 + swz_elem(o & 31, k)] = (bf16_t)v;
    }
    if (i < 192 * 192) {
        int o = i / 192, k = i % 192;
        woutS[(o >> 5) * 6144 + swz_elem(o & 31, k)] = (bf16_t)w_out[k * 192 + o];
    }
}

// ======================= kernel 1: QKV projection GEMM ======================
__global__ __launch_bounds__(256, 4)
void qkv_gemm(const float* __restrict__ x, const float* __restrict__ b_qkv,
              const bf16_t* __restrict__ wqkvS,
              bf16_t* __restrict__ Qg, bf16_t* __restrict__ Kg, bf16_t* __restrict__ Vg)
{
    __shared__ __align__(16) bf16_t Wb[2][6144];     // 24576 B
    __shared__ __align__(16) bf16_t T[4][2][16 * 40]; // 10240 B (wave-private)
    const int tid  = threadIdx.x;
    const int lane = tid & 63;
    const int wave = tid >> 6;
    const int lrow = lane & 15;
    const int lgrp = lane >> 4;
    const int r0   = blockIdx.x * 128 + wave * 32;

    stage_chunk(&Wb[0][0], wqkvS, tid);   // chunk 0

    bf16x8 af[2][6];
#pragma unroll
    for (int tt = 0; tt < 2; ++tt)
#pragma unroll
        for (int ks = 0; ks < 6; ++ks) {
            const float* px = x + (size_t)(r0 + tt * 16 + lrow) * 192 + ks * 32 + lgrp * 8;
            f32x4 lo = *(const f32x4*)px;
            f32x4 hi = *(const f32x4*)(px + 4);
            bf16x8 v;
            v[0] = (bf16_t)lo[0]; v[1] = (bf16_t)lo[1]; v[2] = (bf16_t)lo[2]; v[3] = (bf16_t)lo[3];
            v[4] = (bf16_t)hi[0]; v[5] = (bf16_t)hi[1]; v[6] = (bf16_t)hi[2]; v[7] = (bf16_t)hi[3];
            af[tt][ks] = v;
        }
    __syncthreads();   // chunk 0 resident

    for (int hc = 0; hc < 18; ++hc) {
        if (hc < 17) stage_chunk(&Wb[(hc + 1) & 1][0], wqkvS + (hc + 1) * 6144, tid);
        const bf16_t* wb = &Wb[hc & 1][0];

        f32x4 a[2][2];
        a[0][0] = f32x4{0.f,0.f,0.f,0.f}; a[0][1] = f32x4{0.f,0.f,0.f,0.f};
        a[1][0] = f32x4{0.f,0.f,0.f,0.f}; a[1][1] = f32x4{0.f,0.f,0.f,0.f};
#pragma unroll
        for (int ks = 0; ks < 6; ++ks) {
            bf16x8 wf0 = *(const bf16x8*)&wb[swz_elem(lrow,      ks * 32 + lgrp * 8)];
            bf16x8 wf1 = *(const bf16x8*)&wb[swz_elem(16 + lrow, ks * 32 + lgrp * 8)];
#pragma unroll
            for (int tt = 0; tt < 2; ++tt) {
                a[tt][0] = __builtin_amdgcn_mfma_f32_16x16x32_bf16(af[tt][ks], wf0, a[tt][0], 0, 0, 0);
                a[tt][1] = __builtin_amdgcn_mfma_f32_16x16x32_bf16(af[tt][ks], wf1, a[tt][1], 0, 0, 0);
            }
        }
        __syncthreads();   // chunk hc reads done; stage hc+1 drained

        float b0 = b_qkv[hc * 32 + lrow], b1 = b_qkv[hc * 32 + 16 + lrow];
        if (hc < 6) { b0 *= SCALE; b1 *= SCALE; }
        const int h = (hc < 6) ? hc : (hc < 12) ? hc - 6 : hc - 12;
        bf16_t* dst = (hc < 6) ? Qg : (hc < 12) ? Kg : Vg;
#pragma unroll
        for (int tt = 0; tt < 2; ++tt) {
#pragma unroll
            for (int j = 0; j < 4; ++j) {
                T[wave][tt][(lgrp * 4 + j) * 40 + lrow]      = (bf16_t)(a[tt][0][j] + b0);
                T[wave][tt][(lgrp * 4 + j) * 40 + 16 + lrow] = (bf16_t)(a[tt][1][j] + b1);
            }
            bf16x8 val = *(const bf16x8*)&T[wave][tt][lrow * 40 + lgrp * 8];
            int tk = r0 + tt * 16 + lrow, bw = tk / 144, n = tk % 144;
            *(bf16x8*)&dst[((size_t)(bw * 6 + h) * 144 + n) * 32 + lgrp * 8] = val;
        }
    }
}

// ======================= kernel 1b: Vg (row-major) -> Vt [32][160] ==========
__global__ __launch_bounds__(256, 4)
void vt_transpose(const bf16_t* __restrict__ Vg, bf16_t* __restrict__ Vt)
{
    __shared__ bf16_t tile[4][32 * 168];   // 43008 B
    const int lane = threadIdx.x & 63;
    const int wave = threadIdx.x >> 6;
    const int gid  = blockIdx.x * 4 + wave;          // (bw*6+h) in [0,5952)
    bf16_t* tl = &tile[wave][0];
    const bf16_t* src = Vg + (size_t)gid * 4608;
    bf16_t* dst = Vt + (size_t)gid * 5120;

#pragma unroll
    for (int it = 0; it < 9; ++it) {
        int u = it * 64 + lane;
        int row = u >> 2, dc = u & 3;
        bf16x8 v = *(const bf16x8*)(src + row * 32 + dc * 8);
#pragma unroll
        for (int i = 0; i < 8; ++i) tl[(dc * 8 + i) * 168 + row] = v[i];
    }
    {
        int d = lane >> 1, c = lane & 1;
        bf16x8 z = {};
        *(bf16x8*)&tl[d * 168 + 144 + c * 8] = z;
    }
#pragma unroll
    for (int it = 0; it < 10; ++it) {
        int u = it * 64 + lane;
        int d = u / 20, c = u % 20;
        *(bf16x8*)(dst + d * 160 + c * 8) = *(const bf16x8*)&tl[d * 168 + c * 8];
    }
}

// ======================= kernel 2: attention v5 (batched-load MLP) ==========
// grid 13392 x 256 thr (4 waves). wave-task = (ww, b, h, 16-q-tile), ww-major.
// All fragment loads issued in pinned batches so they stay in flight together.
__global__ __launch_bounds__(256, 4)
void earth_attn_v5(const bf16_t* __restrict__ Qg, const bf16_t* __restrict__ Kg,
                   const bf16_t* __restrict__ Vt,
                   const float* __restrict__ mask, const float* __restrict__ bias,
                   bf16_t* __restrict__ Og)
{
    __shared__ bf16_t P[4][16 * 168];
    const int tid  = threadIdx.x;
    const int lane = tid & 63;
    const int wave = tid >> 6;
    const int lrow = lane & 15;
    const int lgrp = lane >> 4;

    // bijective XCD swizzle: 13392 = 8 * 1674 (contiguous chunk per XCD)
    const int orig = blockIdx.x;
    const int blk  = (orig & 7) * 1674 + (orig >> 3);

    // ww-major task order: one ww's bias slice stays L2-hot per XCD chunk
    const int wid = blk * 4 + wave;          // 0..53567
    const int ww  = wid / 432;               // 0..123
    const int r1  = wid - ww * 432;
    const int b   = r1 / 54;                 // 0..7
    const int rem = r1 - b * 54;
    const int h   = rem / 9;
    const int t0  = (rem % 9) * 16;
    const int bw  = b * 124 + ww;

    const size_t kbase = ((size_t)(bw * 6 + h) * 144) * 32;
    const size_t vbase = ((size_t)(bw * 6 + h) * 32) * 160;

    // ---- batch 1: Q + all 9 K fragments (pinned: 10 loads in flight) -------
    bf16x8 qa = *(const bf16x8*)&Qg[kbase + (size_t)(t0 + lrow) * 32 + lgrp * 8];
    bf16x8 ka[9];
#pragma unroll
    for (int nt = 0; nt < 9; ++nt)
        ka[nt] = *(const bf16x8*)&Kg[kbase + (size_t)(nt * 16 + lrow) * 32 + lgrp * 8];
    PIN(qa);
#pragma unroll
    for (int nt = 0; nt < 9; ++nt) PIN(ka[nt]);

    // ---- batch 2: V fragments (10 loads, hidden under QK + softmax) --------
    bf16x8 va0[5], va1[5];
#pragma unroll
    for (int ks = 0; ks < 5; ++ks) {
        va0[ks] = *(const bf16x8*)&Vt[vbase + (size_t)lrow * 160 + ks * 32 + lgrp * 8];
        va1[ks] = *(const bf16x8*)&Vt[vbase + (size_t)(16 + lrow) * 160 + ks * 32 + lgrp * 8];
    }
#pragma unroll
    for (int ks = 0; ks < 5; ++ks) { PIN(va0[ks]); PIN(va1[ks]); }

    // ---- bias+mask in 3 pinned groups of 6 loads; QK MFMA interleaved ------
    const float* bp = bias + ((size_t)(ww * 6 + h) * 144 + (t0 + lrow)) * 144;
    const float* mp = mask + ((size_t)bw * 144 + (t0 + lrow)) * 144;
    f32x4 s[9];
#pragma unroll
    for (int g = 0; g < 3; ++g) {
        f32x4 bv[3], mv[3];
#pragma unroll
        for (int i = 0; i < 3; ++i) {
            int nt = g * 3 + i;
            bv[i] = *(const f32x4*)(bp + nt * 16 + lgrp * 4);
            mv[i] = *(const f32x4*)(mp + nt * 16 + lgrp * 4);
        }
#pragma unroll
        for (int i = 0; i < 3; ++i) { PIN(bv[i]); PIN(mv[i]); }
#pragma unroll
        for (int i = 0; i < 3; ++i) {
            int nt = g * 3 + i;
            s[nt] = bv[i] + mv[i];
            s[nt] = __builtin_amdgcn_mfma_f32_16x16x32_bf16(ka[nt], qa, s[nt], 0, 0, 0);
        }
    }

    // ---- softmax (lane owns q-row t0+lrow; m spread over lgrp) --------------
    float mx = -1e30f;
#pragma unroll
    for (int nt = 0; nt < 9; ++nt)
#pragma unroll
        for (int j = 0; j < 4; ++j) mx = fmaxf(mx, s[nt][j]);
    mx = fmaxf(mx, __shfl_xor(mx, 16, 64));
    mx = fmaxf(mx, __shfl_xor(mx, 32, 64));
    float sum = 0.f;
#pragma unroll
    for (int nt = 0; nt < 9; ++nt)
#pragma unroll
        for (int j = 0; j < 4; ++j) { float e = __expf(s[nt][j] - mx); s[nt][j] = e; sum += e; }
    sum += __shfl_xor(sum, 16, 64);
    sum += __shfl_xor(sum, 32, 64);
    const float rinv = 1.0f / sum;

    // ---- P -> wave-private LDS, zero tail cols [144,160) --------------------
    bf16_t* pb = &P[wave][0];
#pragma unroll
    for (int nt = 0; nt < 9; ++nt) {
        bf16x4 pw;
#pragma unroll
        for (int j = 0; j < 4; ++j) pw[j] = (bf16_t)(s[nt][j] * rinv);
        *(bf16x4*)&pb[lrow * 168 + nt * 16 + lgrp * 4] = pw;
    }
    {
        uint2 z2 = make_uint2(0u, 0u);
        *(uint2*)&pb[lrow * 168 + 144 + lgrp * 4] = z2;
    }

    // ---- P fragment reads (batched), then PV --------------------------------
    bf16x8 pa[5];
#pragma unroll
    for (int ks = 0; ks < 5; ++ks)
        pa[ks] = *(const bf16x8*)&pb[lrow * 168 + ks * 32 + lgrp * 8];
#pragma unroll
    for (int ks = 0; ks < 5; ++ks) PIN(pa[ks]);

    f32x4 o0{0.f, 0.f, 0.f, 0.f}, o1{0.f, 0.f, 0.f, 0.f};
#pragma unroll
    for (int ks = 0; ks < 5; ++ks) {
        o0 = __builtin_amdgcn_mfma_f32_16x16x32_bf16(pa[ks], va0[ks], o0, 0, 0, 0);
        o1 = __builtin_amdgcn_mfma_f32_16x16x32_bf16(pa[ks], va1[ks], o1, 0, 0, 0);
    }

    // ---- O transpose via pb reuse, coalesced store ---------------------------
#pragma unroll
    for (int j = 0; j < 4; ++j) {
        pb[(lgrp * 4 + j) * 168 + lrow]      = (bf16_t)o0[j];
        pb[(lgrp * 4 + j) * 168 + 16 + lrow] = (bf16_t)o1[j];
    }
    bf16x8 ov = *(const bf16x8*)&pb[lrow * 168 + lgrp * 8];
    *(bf16x8*)&Og[((size_t)bw * 144 + t0 + lrow) * 192 + h * 32 + lgrp * 8] = ov;
}

// ======================= kernel 3: out-projection GEMM ======================
__global__ __launch_bounds__(256, 4)
void out_proj(const bf16_t* __restrict__ Og, const bf16_t* __restrict__ woutS,
              const float* __restrict__ b_out, float* __restrict__ out)
{
    __shared__ __align__(16) bf16_t Wb[2][6144];
    const int tid  = threadIdx.x;
    const int lane = tid & 63;
    const int wave = tid >> 6;
    const int lrow = lane & 15;
    const int lgrp = lane >> 4;
    const size_t row0 = (size_t)blockIdx.x * 64 + wave * 16;

    stage_chunk(&Wb[0][0], woutS, tid);

    bf16x8 af[6];
#pragma unroll
    for (int ks = 0; ks < 6; ++ks)
        af[ks] = *(const bf16x8*)(Og + (row0 + lrow) * 192 + ks * 32 + lgrp * 8);
    __syncthreads();

#pragma unroll
    for (int c = 0; c < 6; ++c) {
        if (c < 5) stage_chunk(&Wb[(c + 1) & 1][0], woutS + (c + 1) * 6144, tid);
        const bf16_t* wb = &Wb[c & 1][0];
        float b0 = b_out[c * 32 + lrow], b1 = b_out[c * 32 + 16 + lrow];
        f32x4 a0{b0, b0, b0, b0}, a1{b1, b1, b1, b1};
#pragma unroll
        for (int ks = 0; ks < 6; ++ks) {
            bf16x8 wf0 = *(const bf16x8*)&wb[swz_elem(lrow,      ks * 32 + lgrp * 8)];
            bf16x8 wf1 = *(const bf16x8*)&wb[swz_elem(16 + lrow, ks * 32 + lgrp * 8)];
            a0 = __builtin_amdgcn_mfma_f32_16x16x32_bf16(af[ks], wf0, a0, 0, 0, 0);
            a1 = __builtin_amdgcn_mfma_f32_16x16x32_bf16(af[ks], wf1, a1, 0, 0, 0);
        }
        __syncthreads();
#pragma unroll
        for (int j = 0; j < 4; ++j) {
            out[(row0 + lgrp * 4 + j) * 192 + c * 32 + lrow]      = a0[j];
            out[(row0 + lgrp * 4 + j) * 192 + c * 32 + 16 + lrow] = a1[j];
        }
    }
}

// ======================= launch =============================================
extern "C" void kernel_launch(void* const* d_in, const int* in_sizes, int n_in,
                              void* d_out, int out_size, void* d_ws, size_t ws_size,
                              hipStream_t stream) {
    const float* x     = (const float*)d_in[0];
    const float* mask  = (const float*)d_in[1];
    const float* w_qkv = (const float*)d_in[2];
    const float* b_qkv = (const float*)d_in[3];
    const float* bias  = (const float*)d_in[4];
    const float* w_out = (const float*)d_in[5];
    const float* b_out = (const float*)d_in[6];

    bf16_t* wqkvS = (bf16_t*)d_ws;                     // 110592 (swizzled chunks)
    bf16_t* woutS = wqkvS + 576 * 192;                 // 36864  (swizzled chunks)
    bf16_t* Qg    = woutS + 192 * 192;                 // 27,426,816
    bf16_t* Kg    = Qg + (size_t)992 * 6 * 144 * 32;   // 27,426,816
    bf16_t* Vt    = Kg + (size_t)992 * 6 * 144 * 32;   // 30,474,240
    bf16_t* Og    = Vt + (size_t)992 * 6 * 32 * 160;   // 27,426,816 (doubles as Vg)
    bf16_t* Vg    = Og;

    prep_weights<<<dim3(432), dim3(256), 0, stream>>>(w_qkv, w_out, wqkvS, woutS);
    qkv_gemm<<<dim3(1116), dim3(256), 0, stream>>>(x, b_qkv, wqkvS, Qg, Kg, Vg);
    vt_transpose<<<dim3(1488), dim3(256), 0, stream>>>(Vg, Vt);
    earth_attn_v5<<<dim3(13392), dim3(256), 0, stream>>>(Qg, Kg, Vt, mask, bias, Og);
    out_proj<<<dim3(2232), dim3(256), 0, stream>>>(Og, woutS, b_out, (float*)d_out);
}

// Round 10
// 269.867 us; speedup vs baseline: 2.4386x; 1.1524x over previous
//
#include <hip/hip_runtime.h>
#include <hip/hip_bf16.h>

typedef __bf16 bf16_t;
typedef bf16_t bf16x8 __attribute__((ext_vector_type(8)));
typedef bf16_t bf16x4 __attribute__((ext_vector_type(4)));
typedef float f32x4 __attribute__((ext_vector_type(4)));

#define SCALE 0.17677669529663687f  // 32^-0.5

// keep a loaded value live / pinned at this program point (defeats load sinking)
#define PIN(x) asm volatile("" : "+v"(x))

// Swizzled element offset within a 32x192 bf16 chunk image (row stride 384 B).
__device__ __forceinline__ int swz_elem(int r, int c) {
    int g = c >> 3;
    return r * 192 + ((g >> 3) << 6) + (((g & 7) ^ (r & 7)) << 3) + (c & 7);
}

// async global->LDS: 16B per lane, linear dest (lane-order = image order)
__device__ __forceinline__ void stage_chunk(bf16_t* dst, const bf16_t* src, int tid) {
#pragma unroll
    for (int it = 0; it < 3; ++it) {
        int off = (it * 256 + tid) * 8;   // 3*256*8 = 6144 elems = 12288 B
        __builtin_amdgcn_global_load_lds(
            (const __attribute__((address_space(1))) unsigned int*)(src + off),
            (__attribute__((address_space(3))) unsigned int*)(dst + off),
            16, 0, 0);
    }
}

// ======================= prep: weights -> swizzled bf16 chunk images ========
__global__ void prep_weights(const float* __restrict__ w_qkv, const float* __restrict__ w_out,
                             bf16_t* __restrict__ wqkvS, bf16_t* __restrict__ woutS) {
    int i = blockIdx.x * 256 + threadIdx.x;
    if (i < 576 * 192) {
        int o = i / 192, k = i % 192;
        float v = w_qkv[k * 576 + o];
        if (o < 192) v *= SCALE;
        wqkvS[(o >> 5) * 6144 + swz_elem(o & 31, k)] = (bf16_t)v;
    }
    if (i < 192 * 192) {
        int o = i / 192, k = i % 192;
        woutS[(o >> 5) * 6144 + swz_elem(o & 31, k)] = (bf16_t)w_out[k * 192 + o];
    }
}

// ======================= kernel 1: QKV projection GEMM ======================
__global__ __launch_bounds__(256, 4)
void qkv_gemm(const float* __restrict__ x, const float* __restrict__ b_qkv,
              const bf16_t* __restrict__ wqkvS,
              bf16_t* __restrict__ Qg, bf16_t* __restrict__ Kg, bf16_t* __restrict__ Vg)
{
    __shared__ __align__(16) bf16_t Wb[2][6144];     // 24576 B
    __shared__ __align__(16) bf16_t T[4][2][16 * 40]; // 10240 B (wave-private)
    const int tid  = threadIdx.x;
    const int lane = tid & 63;
    const int wave = tid >> 6;
    const int lrow = lane & 15;
    const int lgrp = lane >> 4;
    const int r0   = blockIdx.x * 128 + wave * 32;

    stage_chunk(&Wb[0][0], wqkvS, tid);   // chunk 0

    bf16x8 af[2][6];
#pragma unroll
    for (int tt = 0; tt < 2; ++tt)
#pragma unroll
        for (int ks = 0; ks < 6; ++ks) {
            const float* px = x + (size_t)(r0 + tt * 16 + lrow) * 192 + ks * 32 + lgrp * 8;
            f32x4 lo = *(const f32x4*)px;
            f32x4 hi = *(const f32x4*)(px + 4);
            bf16x8 v;
            v[0] = (bf16_t)lo[0]; v[1] = (bf16_t)lo[1]; v[2] = (bf16_t)lo[2]; v[3] = (bf16_t)lo[3];
            v[4] = (bf16_t)hi[0]; v[5] = (bf16_t)hi[1]; v[6] = (bf16_t)hi[2]; v[7] = (bf16_t)hi[3];
            af[tt][ks] = v;
        }
    __syncthreads();   // chunk 0 resident

    for (int hc = 0; hc < 18; ++hc) {
        if (hc < 17) stage_chunk(&Wb[(hc + 1) & 1][0], wqkvS + (hc + 1) * 6144, tid);
        const bf16_t* wb = &Wb[hc & 1][0];

        f32x4 a[2][2];
        a[0][0] = f32x4{0.f,0.f,0.f,0.f}; a[0][1] = f32x4{0.f,0.f,0.f,0.f};
        a[1][0] = f32x4{0.f,0.f,0.f,0.f}; a[1][1] = f32x4{0.f,0.f,0.f,0.f};
#pragma unroll
        for (int ks = 0; ks < 6; ++ks) {
            bf16x8 wf0 = *(const bf16x8*)&wb[swz_elem(lrow,      ks * 32 + lgrp * 8)];
            bf16x8 wf1 = *(const bf16x8*)&wb[swz_elem(16 + lrow, ks * 32 + lgrp * 8)];
#pragma unroll
            for (int tt = 0; tt < 2; ++tt) {
                a[tt][0] = __builtin_amdgcn_mfma_f32_16x16x32_bf16(af[tt][ks], wf0, a[tt][0], 0, 0, 0);
                a[tt][1] = __builtin_amdgcn_mfma_f32_16x16x32_bf16(af[tt][ks], wf1, a[tt][1], 0, 0, 0);
            }
        }
        __syncthreads();   // chunk hc reads done; stage hc+1 drained

        float b0 = b_qkv[hc * 32 + lrow], b1 = b_qkv[hc * 32 + 16 + lrow];
        if (hc < 6) { b0 *= SCALE; b1 *= SCALE; }
        const int h = (hc < 6) ? hc : (hc < 12) ? hc - 6 : hc - 12;
        bf16_t* dst = (hc < 6) ? Qg : (hc < 12) ? Kg : Vg;
#pragma unroll
        for (int tt = 0; tt < 2; ++tt) {
#pragma unroll
            for (int j = 0; j < 4; ++j) {
                T[wave][tt][(lgrp * 4 + j) * 40 + lrow]      = (bf16_t)(a[tt][0][j] + b0);
                T[wave][tt][(lgrp * 4 + j) * 40 + 16 + lrow] = (bf16_t)(a[tt][1][j] + b1);
            }
            bf16x8 val = *(const bf16x8*)&T[wave][tt][lrow * 40 + lgrp * 8];
            int tk = r0 + tt * 16 + lrow, bw = tk / 144, n = tk % 144;
            *(bf16x8*)&dst[((size_t)(bw * 6 + h) * 144 + n) * 32 + lgrp * 8] = val;
        }
    }
}

// ======================= kernel 1b: Vg (row-major) -> Vt [32][160] ==========
__global__ __launch_bounds__(256, 4)
void vt_transpose(const bf16_t* __restrict__ Vg, bf16_t* __restrict__ Vt)
{
    __shared__ bf16_t tile[4][32 * 168];   // 43008 B
    const int lane = threadIdx.x & 63;
    const int wave = threadIdx.x >> 6;
    const int gid  = blockIdx.x * 4 + wave;          // (bw*6+h) in [0,5952)
    bf16_t* tl = &tile[wave][0];
    const bf16_t* src = Vg + (size_t)gid * 4608;
    bf16_t* dst = Vt + (size_t)gid * 5120;

#pragma unroll
    for (int it = 0; it < 9; ++it) {
        int u = it * 64 + lane;
        int row = u >> 2, dc = u & 3;
        bf16x8 v = *(const bf16x8*)(src + row * 32 + dc * 8);
#pragma unroll
        for (int i = 0; i < 8; ++i) tl[(dc * 8 + i) * 168 + row] = v[i];
    }
    {
        int d = lane >> 1, c = lane & 1;
        bf16x8 z = {};
        *(bf16x8*)&tl[d * 168 + 144 + c * 8] = z;
    }
#pragma unroll
    for (int it = 0; it < 10; ++it) {
        int u = it * 64 + lane;
        int d = u / 20, c = u % 20;
        *(bf16x8*)(dst + d * 160 + c * 8) = *(const bf16x8*)&tl[d * 168 + c * 8];
    }
}

// ======================= kernel 2: attention v6 (fused 9-tile wave-task) ====
// grid 1488 x 256 thr (4 waves). wave-task = (bw, h): K/V register-resident,
// loop over the 9 q-tiles; Q prefetched one tile ahead; ZERO barriers.
__global__ __launch_bounds__(256, 2)
void earth_attn_v6(const bf16_t* __restrict__ Qg, const bf16_t* __restrict__ Kg,
                   const bf16_t* __restrict__ Vt,
                   const float* __restrict__ mask, const float* __restrict__ bias,
                   bf16_t* __restrict__ Og)
{
    __shared__ bf16_t P[4][16 * 168];   // 21504 B, wave-private tiles
    const int tid  = threadIdx.x;
    const int lane = tid & 63;
    const int wave = tid >> 6;
    const int lrow = lane & 15;
    const int lgrp = lane >> 4;

    // bijective XCD swizzle: 1488 = 8 * 186 (contiguous chunk per XCD)
    const int orig = blockIdx.x;
    const int blk  = (orig & 7) * 186 + (orig >> 3);

    // ww-major task order (bias slice L2-hot within an XCD chunk)
    const int wid = blk * 4 + wave;          // 0..5951
    const int ww  = wid / 48;                // 0..123
    const int r1  = wid % 48;
    const int b   = r1 / 6;                  // 0..7
    const int h   = r1 % 6;
    const int bw  = b * 124 + ww;

    const size_t kbase = ((size_t)(bw * 6 + h) * 144) * 32;
    const size_t vbase = ((size_t)(bw * 6 + h) * 32) * 160;

    // ---- K fragments: loaded ONCE, register-resident for all 9 q-tiles -----
    bf16x8 ka[9];
#pragma unroll
    for (int nt = 0; nt < 9; ++nt)
        ka[nt] = *(const bf16x8*)&Kg[kbase + (size_t)(nt * 16 + lrow) * 32 + lgrp * 8];

    // ---- V fragments: loaded ONCE, register-resident ------------------------
    bf16x8 va0[5], va1[5];
#pragma unroll
    for (int ks = 0; ks < 5; ++ks) {
        va0[ks] = *(const bf16x8*)&Vt[vbase + (size_t)lrow * 160 + ks * 32 + lgrp * 8];
        va1[ks] = *(const bf16x8*)&Vt[vbase + (size_t)(16 + lrow) * 160 + ks * 32 + lgrp * 8];
    }

    const float* bp_base = bias + (size_t)(ww * 6 + h) * 144 * 144;
    const float* mp_base = mask + (size_t)bw * 144 * 144;
    bf16_t* pb = &P[wave][0];
    bf16_t* ogp = Og + ((size_t)bw * 144) * 192 + h * 32 + lgrp * 8;

    // Q for tile 0; tiles prefetched one ahead inside the loop
    bf16x8 qa = *(const bf16x8*)&Qg[kbase + (size_t)lrow * 32 + lgrp * 8];

#pragma unroll 1
    for (int t = 0; t < 9; ++t) {
        // prefetch next tile's Q (clamped; latency hides under this tile)
        const int tn = (t < 8) ? t + 1 : 8;
        bf16x8 qa_n = *(const bf16x8*)&Qg[kbase + (size_t)(tn * 16 + lrow) * 32 + lgrp * 8];

        // ---- S^T = K Q^T + (bias+mask); loads in pinned groups of 6 --------
        const float* bp = bp_base + (size_t)(t * 16 + lrow) * 144;
        const float* mp = mp_base + (size_t)(t * 16 + lrow) * 144;
        f32x4 s[9];
#pragma unroll
        for (int g = 0; g < 3; ++g) {
            f32x4 bv[3], mv[3];
#pragma unroll
            for (int i = 0; i < 3; ++i) {
                int nt = g * 3 + i;
                bv[i] = *(const f32x4*)(bp + nt * 16 + lgrp * 4);
                mv[i] = *(const f32x4*)(mp + nt * 16 + lgrp * 4);
            }
#pragma unroll
            for (int i = 0; i < 3; ++i) { PIN(bv[i]); PIN(mv[i]); }
#pragma unroll
            for (int i = 0; i < 3; ++i) {
                int nt = g * 3 + i;
                s[nt] = bv[i] + mv[i];
                s[nt] = __builtin_amdgcn_mfma_f32_16x16x32_bf16(ka[nt], qa, s[nt], 0, 0, 0);
            }
        }

        // ---- softmax (lane owns q-row t*16+lrow; m spread over lgrp) -------
        float mx = -1e30f;
#pragma unroll
        for (int nt = 0; nt < 9; ++nt)
#pragma unroll
            for (int j = 0; j < 4; ++j) mx = fmaxf(mx, s[nt][j]);
        mx = fmaxf(mx, __shfl_xor(mx, 16, 64));
        mx = fmaxf(mx, __shfl_xor(mx, 32, 64));
        float sum = 0.f;
#pragma unroll
        for (int nt = 0; nt < 9; ++nt)
#pragma unroll
            for (int j = 0; j < 4; ++j) { float e = __expf(s[nt][j] - mx); s[nt][j] = e; sum += e; }
        sum += __shfl_xor(sum, 16, 64);
        sum += __shfl_xor(sum, 32, 64);
        const float rinv = 1.0f / sum;

        // ---- P -> wave-private LDS, zero tail cols [144,160) ----------------
#pragma unroll
        for (int nt = 0; nt < 9; ++nt) {
            bf16x4 pw;
#pragma unroll
            for (int j = 0; j < 4; ++j) pw[j] = (bf16_t)(s[nt][j] * rinv);
            *(bf16x4*)&pb[lrow * 168 + nt * 16 + lgrp * 4] = pw;
        }
        {
            uint2 z2 = make_uint2(0u, 0u);
            *(uint2*)&pb[lrow * 168 + 144 + lgrp * 4] = z2;
        }

        // ---- P fragments, PV MFMAs ------------------------------------------
        bf16x8 pa[5];
#pragma unroll
        for (int ks = 0; ks < 5; ++ks)
            pa[ks] = *(const bf16x8*)&pb[lrow * 168 + ks * 32 + lgrp * 8];
#pragma unroll
        for (int ks = 0; ks < 5; ++ks) PIN(pa[ks]);

        f32x4 o0{0.f, 0.f, 0.f, 0.f}, o1{0.f, 0.f, 0.f, 0.f};
#pragma unroll
        for (int ks = 0; ks < 5; ++ks) {
            o0 = __builtin_amdgcn_mfma_f32_16x16x32_bf16(pa[ks], va0[ks], o0, 0, 0, 0);
            o1 = __builtin_amdgcn_mfma_f32_16x16x32_bf16(pa[ks], va1[ks], o1, 0, 0, 0);
        }

        // ---- O transpose via pb reuse (wave-private, in-order), store -------
#pragma unroll
        for (int j = 0; j < 4; ++j) {
            pb[(lgrp * 4 + j) * 168 + lrow]      = (bf16_t)o0[j];
            pb[(lgrp * 4 + j) * 168 + 16 + lrow] = (bf16_t)o1[j];
        }
        bf16x8 ov = *(const bf16x8*)&pb[lrow * 168 + lgrp * 8];
        *(bf16x8*)(ogp + (size_t)(t * 16 + lrow) * 192) = ov;

        qa = qa_n;
    }
}

// ======================= kernel 3: out-projection GEMM ======================
__global__ __launch_bounds__(256, 4)
void out_proj(const bf16_t* __restrict__ Og, const bf16_t* __restrict__ woutS,
              const float* __restrict__ b_out, float* __restrict__ out)
{
    __shared__ __align__(16) bf16_t Wb[2][6144];
    const int tid  = threadIdx.x;
    const int lane = tid & 63;
    const int wave = tid >> 6;
    const int lrow = lane & 15;
    const int lgrp = lane >> 4;
    const size_t row0 = (size_t)blockIdx.x * 64 + wave * 16;

    stage_chunk(&Wb[0][0], woutS, tid);

    bf16x8 af[6];
#pragma unroll
    for (int ks = 0; ks < 6; ++ks)
        af[ks] = *(const bf16x8*)(Og + (row0 + lrow) * 192 + ks * 32 + lgrp * 8);
    __syncthreads();

#pragma unroll
    for (int c = 0; c < 6; ++c) {
        if (c < 5) stage_chunk(&Wb[(c + 1) & 1][0], woutS + (c + 1) * 6144, tid);
        const bf16_t* wb = &Wb[c & 1][0];
        float b0 = b_out[c * 32 + lrow], b1 = b_out[c * 32 + 16 + lrow];
        f32x4 a0{b0, b0, b0, b0}, a1{b1, b1, b1, b1};
#pragma unroll
        for (int ks = 0; ks < 6; ++ks) {
            bf16x8 wf0 = *(const bf16x8*)&wb[swz_elem(lrow,      ks * 32 + lgrp * 8)];
            bf16x8 wf1 = *(const bf16x8*)&wb[swz_elem(16 + lrow, ks * 32 + lgrp * 8)];
            a0 = __builtin_amdgcn_mfma_f32_16x16x32_bf16(af[ks], wf0, a0, 0, 0, 0);
            a1 = __builtin_amdgcn_mfma_f32_16x16x32_bf16(af[ks], wf1, a1, 0, 0, 0);
        }
        __syncthreads();
#pragma unroll
        for (int j = 0; j < 4; ++j) {
            out[(row0 + lgrp * 4 + j) * 192 + c * 32 + lrow]      = a0[j];
            out[(row0 + lgrp * 4 + j) * 192 + c * 32 + 16 + lrow] = a1[j];
        }
    }
}

// ======================= launch =============================================
extern "C" void kernel_launch(void* const* d_in, const int* in_sizes, int n_in,
                              void* d_out, int out_size, void* d_ws, size_t ws_size,
                              hipStream_t stream) {
    const float* x     = (const float*)d_in[0];
    const float* mask  = (const float*)d_in[1];
    const float* w_qkv = (const float*)d_in[2];
    const float* b_qkv = (const float*)d_in[3];
    const float* bias  = (const float*)d_in[4];
    const float* w_out = (const float*)d_in[5];
    const float* b_out = (const float*)d_in[6];

    bf16_t* wqkvS = (bf16_t*)d_ws;                     // 110592 (swizzled chunks)
    bf16_t* woutS = wqkvS + 576 * 192;                 // 36864  (swizzled chunks)
    bf16_t* Qg    = woutS + 192 * 192;                 // 27,426,816
    bf16_t* Kg    = Qg + (size_t)992 * 6 * 144 * 32;   // 27,426,816
    bf16_t* Vt    = Kg + (size_t)992 * 6 * 144 * 32;   // 30,474,240
    bf16_t* Og    = Vt + (size_t)992 * 6 * 32 * 160;   // 27,426,816 (doubles as Vg)
    bf16_t* Vg    = Og;

    prep_weights<<<dim3(432), dim3(256), 0, stream>>>(w_qkv, w_out, wqkvS, woutS);
    qkv_gemm<<<dim3(1116), dim3(256), 0, stream>>>(x, b_qkv, wqkvS, Qg, Kg, Vg);
    vt_transpose<<<dim3(1488), dim3(256), 0, stream>>>(Vg, Vt);
    earth_attn_v6<<<dim3(1488), dim3(256), 0, stream>>>(Qg, Kg, Vt, mask, bias, Og);
    out_proj<<<dim3(2232), dim3(256), 0, stream>>>(Og, woutS, b_out, (float*)d_out);
}

// Round 11
// 263.579 us; speedup vs baseline: 2.4968x; 1.0239x over previous
//
#include <hip/hip_runtime.h>
#include <hip/hip_bf16.h>

typedef __bf16 bf16_t;
typedef bf16_t bf16x8 __attribute__((ext_vector_type(8)));
typedef bf16_t bf16x4 __attribute__((ext_vector_type(4)));
typedef float f32x4 __attribute__((ext_vector_type(4)));

#define SCALE 0.17677669529663687f  // 32^-0.5

// keep a loaded value live / pinned at this program point (defeats load sinking)
#define PIN(x) asm volatile("" : "+v"(x))

// Swizzled element offset within a 32x192 bf16 chunk image (row stride 384 B).
__device__ __forceinline__ int swz_elem(int r, int c) {
    int g = c >> 3;
    return r * 192 + ((g >> 3) << 6) + (((g & 7) ^ (r & 7)) << 3) + (c & 7);
}

// async global->LDS: 16B per lane, linear dest (lane-order = image order)
__device__ __forceinline__ void stage_chunk(bf16_t* dst, const bf16_t* src, int tid) {
#pragma unroll
    for (int it = 0; it < 3; ++it) {
        int off = (it * 256 + tid) * 8;   // 3*256*8 = 6144 elems = 12288 B
        __builtin_amdgcn_global_load_lds(
            (const __attribute__((address_space(1))) unsigned int*)(src + off),
            (__attribute__((address_space(3))) unsigned int*)(dst + off),
            16, 0, 0);
    }
}

// ======================= prep: weights -> swizzled bf16 chunk images ========
__global__ void prep_weights(const float* __restrict__ w_qkv, const float* __restrict__ w_out,
                             bf16_t* __restrict__ wqkvS, bf16_t* __restrict__ woutS) {
    int i = blockIdx.x * 256 + threadIdx.x;
    if (i < 576 * 192) {
        int o = i / 192, k = i % 192;
        float v = w_qkv[k * 576 + o];
        if (o < 192) v *= SCALE;
        wqkvS[(o >> 5) * 6144 + swz_elem(o & 31, k)] = (bf16_t)v;
    }
    if (i < 192 * 192) {
        int o = i / 192, k = i % 192;
        woutS[(o >> 5) * 6144 + swz_elem(o & 31, k)] = (bf16_t)w_out[k * 192 + o];
    }
}

// ======================= kernel 1: QKV projection GEMM ======================
// grid 1116 x 256 thr (4 waves); wave = 32 token-rows. Weight chunks double-
// buffered in LDS via global_load_lds. Q/K stored row-major via T-transpose;
// V stored DIRECTLY TRANSPOSED into Vt[bw*6+h][d][n] via the same T tile.
__global__ __launch_bounds__(256, 4)
void qkv_gemm(const float* __restrict__ x, const float* __restrict__ b_qkv,
              const bf16_t* __restrict__ wqkvS,
              bf16_t* __restrict__ Qg, bf16_t* __restrict__ Kg, bf16_t* __restrict__ Vt)
{
    __shared__ __align__(16) bf16_t Wb[2][6144];      // 24576 B
    __shared__ __align__(16) bf16_t T[4][1280];       // 10240 B (wave-private)
    const int tid  = threadIdx.x;
    const int lane = tid & 63;
    const int wave = tid >> 6;
    const int lrow = lane & 15;
    const int lgrp = lane >> 4;
    const int r0   = blockIdx.x * 128 + wave * 32;

    stage_chunk(&Wb[0][0], wqkvS, tid);   // chunk 0

    bf16x8 af[2][6];
#pragma unroll
    for (int tt = 0; tt < 2; ++tt)
#pragma unroll
        for (int ks = 0; ks < 6; ++ks) {
            const float* px = x + (size_t)(r0 + tt * 16 + lrow) * 192 + ks * 32 + lgrp * 8;
            f32x4 lo = *(const f32x4*)px;
            f32x4 hi = *(const f32x4*)(px + 4);
            bf16x8 v;
            v[0] = (bf16_t)lo[0]; v[1] = (bf16_t)lo[1]; v[2] = (bf16_t)lo[2]; v[3] = (bf16_t)lo[3];
            v[4] = (bf16_t)hi[0]; v[5] = (bf16_t)hi[1]; v[6] = (bf16_t)hi[2]; v[7] = (bf16_t)hi[3];
            af[tt][ks] = v;
        }
    __syncthreads();   // chunk 0 resident

    bf16_t* tl = &T[wave][0];

    for (int hc = 0; hc < 18; ++hc) {
        if (hc < 17) stage_chunk(&Wb[(hc + 1) & 1][0], wqkvS + (hc + 1) * 6144, tid);
        const bf16_t* wb = &Wb[hc & 1][0];

        f32x4 a[2][2];
        a[0][0] = f32x4{0.f,0.f,0.f,0.f}; a[0][1] = f32x4{0.f,0.f,0.f,0.f};
        a[1][0] = f32x4{0.f,0.f,0.f,0.f}; a[1][1] = f32x4{0.f,0.f,0.f,0.f};
#pragma unroll
        for (int ks = 0; ks < 6; ++ks) {
            bf16x8 wf0 = *(const bf16x8*)&wb[swz_elem(lrow,      ks * 32 + lgrp * 8)];
            bf16x8 wf1 = *(const bf16x8*)&wb[swz_elem(16 + lrow, ks * 32 + lgrp * 8)];
#pragma unroll
            for (int tt = 0; tt < 2; ++tt) {
                a[tt][0] = __builtin_amdgcn_mfma_f32_16x16x32_bf16(af[tt][ks], wf0, a[tt][0], 0, 0, 0);
                a[tt][1] = __builtin_amdgcn_mfma_f32_16x16x32_bf16(af[tt][ks], wf1, a[tt][1], 0, 0, 0);
            }
        }
        __syncthreads();   // chunk hc reads done; stage hc+1 drained

        float b0 = b_qkv[hc * 32 + lrow], b1 = b_qkv[hc * 32 + 16 + lrow];
        if (hc < 6) { b0 *= SCALE; b1 *= SCALE; }

        if (hc < 12) {
            // ---- Q/K: per-16-row T transpose, coalesced row-major store -----
            const int h = (hc < 6) ? hc : hc - 6;
            bf16_t* dst = (hc < 6) ? Qg : Kg;
#pragma unroll
            for (int tt = 0; tt < 2; ++tt) {
#pragma unroll
                for (int j = 0; j < 4; ++j) {
                    tl[tt * 640 + (lgrp * 4 + j) * 40 + lrow]      = (bf16_t)(a[tt][0][j] + b0);
                    tl[tt * 640 + (lgrp * 4 + j) * 40 + 16 + lrow] = (bf16_t)(a[tt][1][j] + b1);
                }
                bf16x8 val = *(const bf16x8*)&tl[tt * 640 + lrow * 40 + lgrp * 8];
                int tk = r0 + tt * 16 + lrow, bw = tk / 144, n = tk % 144;
                *(bf16x8*)&dst[((size_t)(bw * 6 + h) * 144 + n) * 32 + lgrp * 8] = val;
            }
        } else {
            // ---- V: d-major tile in T, store transposed [d][n] --------------
            const int hv = hc - 12;
#pragma unroll
            for (int tt = 0; tt < 2; ++tt)
#pragma unroll
                for (int j = 0; j < 4; ++j) {
                    tl[(lrow) * 40      + tt * 16 + lgrp * 4 + j] = (bf16_t)(a[tt][0][j] + b0);
                    tl[(16 + lrow) * 40 + tt * 16 + lgrp * 4 + j] = (bf16_t)(a[tt][1][j] + b1);
                }
#pragma unroll
            for (int it = 0; it < 2; ++it) {
                int slot = it * 64 + lane;          // 128 slots = 32 d x 4 col-groups
                int d = slot >> 2, c = slot & 3;    // c*8 = 8-token group (8 | 144)
                int tk = r0 + c * 8, bw = tk / 144, n = tk % 144;
                bf16x8 val = *(const bf16x8*)&tl[d * 40 + c * 8];
                *(bf16x8*)&Vt[((size_t)(bw * 6 + hv) * 32 + d) * 160 + n] = val;
            }
        }
    }
}

// ======================= kernel 2: attention v7 (bias/mask pipelined) =======
// grid 1488 x 256 thr (4 waves). wave-task = (bw, h): K/V register-resident,
// 9 q-tiles; Q and bias+mask prefetched one tile ahead. ZERO barriers.
__global__ __launch_bounds__(256, 2)
void earth_attn_v7(const bf16_t* __restrict__ Qg, const bf16_t* __restrict__ Kg,
                   const bf16_t* __restrict__ Vt,
                   const float* __restrict__ mask, const float* __restrict__ bias,
                   bf16_t* __restrict__ Og)
{
    __shared__ bf16_t P[4][16 * 168];   // 21504 B, wave-private tiles
    const int tid  = threadIdx.x;
    const int lane = tid & 63;
    const int wave = tid >> 6;
    const int lrow = lane & 15;
    const int lgrp = lane >> 4;

    // bijective XCD swizzle: 1488 = 8 * 186 (contiguous chunk per XCD)
    const int orig = blockIdx.x;
    const int blk  = (orig & 7) * 186 + (orig >> 3);

    // ww-major task order (bias slice L2-hot within an XCD chunk)
    const int wid = blk * 4 + wave;          // 0..5951
    const int ww  = wid / 48;                // 0..123
    const int r1  = wid % 48;
    const int b   = r1 / 6;                  // 0..7
    const int h   = r1 % 6;
    const int bw  = b * 124 + ww;

    const size_t kbase = ((size_t)(bw * 6 + h) * 144) * 32;
    const size_t vbase = ((size_t)(bw * 6 + h) * 32) * 160;

    // ---- K fragments: loaded ONCE, register-resident for all 9 q-tiles -----
    bf16x8 ka[9];
#pragma unroll
    for (int nt = 0; nt < 9; ++nt)
        ka[nt] = *(const bf16x8*)&Kg[kbase + (size_t)(nt * 16 + lrow) * 32 + lgrp * 8];

    // ---- V fragments: loaded ONCE, register-resident ------------------------
    bf16x8 va0[5], va1[5];
#pragma unroll
    for (int ks = 0; ks < 5; ++ks) {
        va0[ks] = *(const bf16x8*)&Vt[vbase + (size_t)lrow * 160 + ks * 32 + lgrp * 8];
        va1[ks] = *(const bf16x8*)&Vt[vbase + (size_t)(16 + lrow) * 160 + ks * 32 + lgrp * 8];
    }

    const float* bp_base = bias + (size_t)(ww * 6 + h) * 144 * 144;
    const float* mp_base = mask + (size_t)bw * 144 * 144;
    bf16_t* pb = &P[wave][0];
    bf16_t* ogp = Og + ((size_t)bw * 144) * 192 + h * 32 + lgrp * 8;

    // ---- preload tile 0: Q + bias/mask --------------------------------------
    bf16x8 qa = *(const bf16x8*)&Qg[kbase + (size_t)lrow * 32 + lgrp * 8];
    f32x4 bv[9], mv[9];
    {
        const float* bp = bp_base + (size_t)lrow * 144;
        const float* mp = mp_base + (size_t)lrow * 144;
#pragma unroll
        for (int nt = 0; nt < 9; ++nt) {
            bv[nt] = *(const f32x4*)(bp + nt * 16 + lgrp * 4);
            mv[nt] = *(const f32x4*)(mp + nt * 16 + lgrp * 4);
        }
    }

#pragma unroll 1
    for (int t = 0; t < 9; ++t) {
        // ---- consume prefetched bias/mask into S C-init ----------------------
        f32x4 s[9];
#pragma unroll
        for (int nt = 0; nt < 9; ++nt) s[nt] = bv[nt] + mv[nt];

        // ---- issue NEXT tile's Q + bias/mask (hidden under MFMA/softmax/PV) --
        const int tn = (t < 8) ? t + 1 : 8;
        bf16x8 qa_n = *(const bf16x8*)&Qg[kbase + (size_t)(tn * 16 + lrow) * 32 + lgrp * 8];
        PIN(qa_n);
        {
            const float* bp = bp_base + (size_t)(tn * 16 + lrow) * 144;
            const float* mp = mp_base + (size_t)(tn * 16 + lrow) * 144;
#pragma unroll
            for (int nt = 0; nt < 9; ++nt) {
                bv[nt] = *(const f32x4*)(bp + nt * 16 + lgrp * 4);
                mv[nt] = *(const f32x4*)(mp + nt * 16 + lgrp * 4);
            }
#pragma unroll
            for (int nt = 0; nt < 9; ++nt) { PIN(bv[nt]); PIN(mv[nt]); }
        }

        // ---- S^T = K Q^T + C-init (all register operands) --------------------
#pragma unroll
        for (int nt = 0; nt < 9; ++nt)
            s[nt] = __builtin_amdgcn_mfma_f32_16x16x32_bf16(ka[nt], qa, s[nt], 0, 0, 0);

        // ---- softmax (lane owns q-row t*16+lrow; m spread over lgrp) ---------
        float mx = -1e30f;
#pragma unroll
        for (int nt = 0; nt < 9; ++nt)
#pragma unroll
            for (int j = 0; j < 4; ++j) mx = fmaxf(mx, s[nt][j]);
        mx = fmaxf(mx, __shfl_xor(mx, 16, 64));
        mx = fmaxf(mx, __shfl_xor(mx, 32, 64));
        float sum = 0.f;
#pragma unroll
        for (int nt = 0; nt < 9; ++nt)
#pragma unroll
            for (int j = 0; j < 4; ++j) { float e = __expf(s[nt][j] - mx); s[nt][j] = e; sum += e; }
        sum += __shfl_xor(sum, 16, 64);
        sum += __shfl_xor(sum, 32, 64);
        const float rinv = 1.0f / sum;

        // ---- P -> wave-private LDS, zero tail cols [144,160) -----------------
#pragma unroll
        for (int nt = 0; nt < 9; ++nt) {
            bf16x4 pw;
#pragma unroll
            for (int j = 0; j < 4; ++j) pw[j] = (bf16_t)(s[nt][j] * rinv);
            *(bf16x4*)&pb[lrow * 168 + nt * 16 + lgrp * 4] = pw;
        }
        {
            uint2 z2 = make_uint2(0u, 0u);
            *(uint2*)&pb[lrow * 168 + 144 + lgrp * 4] = z2;
        }

        // ---- P fragments, PV MFMAs (Vt tail cols are garbage x zero P = 0) ---
        bf16x8 pa[5];
#pragma unroll
        for (int ks = 0; ks < 5; ++ks)
            pa[ks] = *(const bf16x8*)&pb[lrow * 168 + ks * 32 + lgrp * 8];
#pragma unroll
        for (int ks = 0; ks < 5; ++ks) PIN(pa[ks]);

        f32x4 o0{0.f, 0.f, 0.f, 0.f}, o1{0.f, 0.f, 0.f, 0.f};
#pragma unroll
        for (int ks = 0; ks < 5; ++ks) {
            o0 = __builtin_amdgcn_mfma_f32_16x16x32_bf16(pa[ks], va0[ks], o0, 0, 0, 0);
            o1 = __builtin_amdgcn_mfma_f32_16x16x32_bf16(pa[ks], va1[ks], o1, 0, 0, 0);
        }

        // ---- O transpose via pb reuse (wave-private, in-order), store --------
#pragma unroll
        for (int j = 0; j < 4; ++j) {
            pb[(lgrp * 4 + j) * 168 + lrow]      = (bf16_t)o0[j];
            pb[(lgrp * 4 + j) * 168 + 16 + lrow] = (bf16_t)o1[j];
        }
        bf16x8 ov = *(const bf16x8*)&pb[lrow * 168 + lgrp * 8];
        *(bf16x8*)(ogp + (size_t)(t * 16 + lrow) * 192) = ov;

        qa = qa_n;
    }
}

// ======================= kernel 3: out-projection GEMM ======================
__global__ __launch_bounds__(256, 4)
void out_proj(const bf16_t* __restrict__ Og, const bf16_t* __restrict__ woutS,
              const float* __restrict__ b_out, float* __restrict__ out)
{
    __shared__ __align__(16) bf16_t Wb[2][6144];
    const int tid  = threadIdx.x;
    const int lane = tid & 63;
    const int wave = tid >> 6;
    const int lrow = lane & 15;
    const int lgrp = lane >> 4;
    const size_t row0 = (size_t)blockIdx.x * 64 + wave * 16;

    stage_chunk(&Wb[0][0], woutS, tid);

    bf16x8 af[6];
#pragma unroll
    for (int ks = 0; ks < 6; ++ks)
        af[ks] = *(const bf16x8*)(Og + (row0 + lrow) * 192 + ks * 32 + lgrp * 8);
    __syncthreads();

#pragma unroll
    for (int c = 0; c < 6; ++c) {
        if (c < 5) stage_chunk(&Wb[(c + 1) & 1][0], woutS + (c + 1) * 6144, tid);
        const bf16_t* wb = &Wb[c & 1][0];
        float b0 = b_out[c * 32 + lrow], b1 = b_out[c * 32 + 16 + lrow];
        f32x4 a0{b0, b0, b0, b0}, a1{b1, b1, b1, b1};
#pragma unroll
        for (int ks = 0; ks < 6; ++ks) {
            bf16x8 wf0 = *(const bf16x8*)&wb[swz_elem(lrow,      ks * 32 + lgrp * 8)];
            bf16x8 wf1 = *(const bf16x8*)&wb[swz_elem(16 + lrow, ks * 32 + lgrp * 8)];
            a0 = __builtin_amdgcn_mfma_f32_16x16x32_bf16(af[ks], wf0, a0, 0, 0, 0);
            a1 = __builtin_amdgcn_mfma_f32_16x16x32_bf16(af[ks], wf1, a1, 0, 0, 0);
        }
        __syncthreads();
#pragma unroll
        for (int j = 0; j < 4; ++j) {
            out[(row0 + lgrp * 4 + j) * 192 + c * 32 + lrow]      = a0[j];
            out[(row0 + lgrp * 4 + j) * 192 + c * 32 + 16 + lrow] = a1[j];
        }
    }
}

// ======================= launch =============================================
extern "C" void kernel_launch(void* const* d_in, const int* in_sizes, int n_in,
                              void* d_out, int out_size, void* d_ws, size_t ws_size,
                              hipStream_t stream) {
    const float* x     = (const float*)d_in[0];
    const float* mask  = (const float*)d_in[1];
    const float* w_qkv = (const float*)d_in[2];
    const float* b_qkv = (const float*)d_in[3];
    const float* bias  = (const float*)d_in[4];
    const float* w_out = (const float*)d_in[5];
    const float* b_out = (const float*)d_in[6];

    bf16_t* wqkvS = (bf16_t*)d_ws;                     // 110592 (swizzled chunks)
    bf16_t* woutS = wqkvS + 576 * 192;                 // 36864  (swizzled chunks)
    bf16_t* Qg    = woutS + 192 * 192;                 // 27,426,816
    bf16_t* Kg    = Qg + (size_t)992 * 6 * 144 * 32;   // 27,426,816
    bf16_t* Vt    = Kg + (size_t)992 * 6 * 144 * 32;   // 30,474,240
    bf16_t* Og    = Vt + (size_t)992 * 6 * 32 * 160;   // 27,426,816

    prep_weights<<<dim3(432), dim3(256), 0, stream>>>(w_qkv, w_out, wqkvS, woutS);
    qkv_gemm<<<dim3(1116), dim3(256), 0, stream>>>(x, b_qkv, wqkvS, Qg, Kg, Vt);
    earth_attn_v7<<<dim3(1488), dim3(256), 0, stream>>>(Qg, Kg, Vt, mask, bias, Og);
    out_proj<<<dim3(2232), dim3(256), 0, stream>>>(Og, woutS, b_out, (float*)d_out);
}